// Round 1
// baseline (1257.935 us; speedup 1.0000x reference)
//
#include <hip/hip_runtime.h>

#define BB 8
#define TT 2048
#define CC 1024
// M = BB*TT = 16384

typedef __bf16 bf16x8_t __attribute__((ext_vector_type(8)));
typedef float f32x4_t __attribute__((ext_vector_type(4)));

__device__ __forceinline__ unsigned short f2bf(float f) {
  unsigned u = __float_as_uint(f);
  u += 0x7fffu + ((u >> 16) & 1u);   // round-to-nearest-even
  return (unsigned short)(u >> 16);
}
__device__ __forceinline__ float bf2f(unsigned short s) {
  return __uint_as_float(((unsigned)s) << 16);
}

// xk = x*tm + xshift*(1-tm), cast to bf16.  One row = (b,t); shift is t-1 within batch.
__global__ __launch_bounds__(256) void mix_cast_kernel(const float* __restrict__ x,
                                const float* __restrict__ tmix,
                                unsigned short* __restrict__ out) {
  const size_t total4 = (size_t)BB * TT * CC / 4;
  for (size_t i = (size_t)blockIdx.x * blockDim.x + threadIdx.x; i < total4;
       i += (size_t)gridDim.x * blockDim.x) {
    size_t e = i * 4;
    int c = (int)(e & (CC - 1));
    int t = (int)((e / CC) & (TT - 1));
    float4 xv = ((const float4*)x)[i];
    float4 xp = make_float4(0.f, 0.f, 0.f, 0.f);
    if (t > 0) xp = ((const float4*)x)[i - CC / 4];
    float4 tm = *(const float4*)(tmix + c);
    ushort4 o;
    o.x = f2bf(xv.x * tm.x + xp.x * (1.f - tm.x));
    o.y = f2bf(xv.y * tm.y + xp.y * (1.f - tm.y));
    o.z = f2bf(xv.z * tm.z + xp.z * (1.f - tm.z));
    o.w = f2bf(xv.w * tm.w + xp.w * (1.f - tm.w));
    *(ushort4*)(out + e) = o;
  }
}

__global__ __launch_bounds__(256) void cast_w_kernel(const float* __restrict__ w,
                              unsigned short* __restrict__ out, int n4) {
  for (int i = blockIdx.x * blockDim.x + threadIdx.x; i < n4;
       i += gridDim.x * blockDim.x) {
    float4 v = ((const float4*)w)[i];
    ushort4 o;
    o.x = f2bf(v.x); o.y = f2bf(v.y); o.z = f2bf(v.z); o.w = f2bf(v.w);
    ((ushort4*)out)[i] = o;
  }
}

// C[m,n] = sum_k A[m,k] * B[n,k]   (A:[M,K] bf16 row-major, B:[N,K] bf16 row-major)
// One wave computes a 64x64 output tile (4x4 grid of 16x16 MFMA frags).
template <int OUT_BF16>
__global__ __launch_bounds__(256) void gemm_bt(const unsigned short* __restrict__ A,
                        const unsigned short* __restrict__ Bm,
                        void* __restrict__ Cm, int M, int N, int K) {
  int wid = (blockIdx.x << 2) + (threadIdx.x >> 6);
  int lane = threadIdx.x & 63;
  int tiles_n = N >> 6;
  int tm = wid / tiles_n;
  int tn = wid - tm * tiles_n;
  if (tm >= (M >> 6)) return;
  int rr = lane & 15;          // fragment row (A) / row of B (=output col)
  int kg = (lane >> 4) << 3;   // k-subgroup offset: 8 contiguous k per lane group
  const unsigned short* Ap = A + (size_t)(tm * 64 + rr) * K + kg;
  const unsigned short* Bp = Bm + (size_t)(tn * 64 + rr) * K + kg;

  f32x4_t acc[4][4] = {};
  for (int k0 = 0; k0 < K; k0 += 32) {
    bf16x8_t a[4], b[4];
#pragma unroll
    for (int i = 0; i < 4; ++i) {
      a[i] = *(const bf16x8_t*)(Ap + (size_t)i * 16 * K + k0);
      b[i] = *(const bf16x8_t*)(Bp + (size_t)i * 16 * K + k0);
    }
#pragma unroll
    for (int i = 0; i < 4; ++i)
#pragma unroll
      for (int j = 0; j < 4; ++j)
        acc[i][j] = __builtin_amdgcn_mfma_f32_16x16x32_bf16(a[i], b[j], acc[i][j], 0, 0, 0);
  }

  // C/D layout (m89-verified): col = lane&15, row = (lane>>4)*4 + reg
  int orow0 = tm * 64 + ((lane >> 4) << 2);
  int ocol0 = tn * 64 + (lane & 15);
#pragma unroll
  for (int i = 0; i < 4; ++i)
#pragma unroll
    for (int j = 0; j < 4; ++j)
#pragma unroll
      for (int rg = 0; rg < 4; ++rg) {
        size_t row = (size_t)(orow0 + i * 16 + rg);
        size_t col = (size_t)(ocol0 + j * 16);
        if (OUT_BF16)
          ((unsigned short*)Cm)[row * N + col] = f2bf(acc[i][j][rg]);
        else
          ((float*)Cm)[row * N + col] = acc[i][j][rg];
      }
}

// Numerically-stable WKV recurrence, one thread per (b,c); fuses sigmoid(r)*y,
// writes bf16 rwkv.
__global__ __launch_bounds__(256) void wkv_kernel(const float* __restrict__ k,
                           const float* __restrict__ v,
                           const unsigned short* __restrict__ r,
                           const float* __restrict__ wdec,
                           const float* __restrict__ u,
                           unsigned short* __restrict__ out) {
  int idx = blockIdx.x * blockDim.x + threadIdx.x;
  if (idx >= BB * CC) return;
  int b = idx >> 10;
  int c = idx & (CC - 1);
  float w = -__expf(wdec[c]);
  float uu = u[c];
  size_t base = (size_t)b * TT * CC + c;
  float aa = 0.f, bb = 0.f, pp = -1e38f;
  for (int t = 0; t < TT; ++t) {
    size_t off = base + (size_t)t * CC;
    float kt = k[off];
    float vt = v[off];
    float ww = uu + kt;
    float q = fmaxf(pp, ww);
    float e1 = __expf(pp - q);
    float e2 = __expf(ww - q);
    float y = fmaf(e1, aa, e2 * vt) / fmaf(e1, bb, e2);
    float ww2 = pp + w;
    float q2 = fmaxf(ww2, kt);
    float f1 = __expf(ww2 - q2);
    float f2 = __expf(kt - q2);
    aa = fmaf(f1, aa, f2 * vt);
    bb = fmaf(f1, bb, f2);
    pp = q2;
    float rt = bf2f(r[off]);
    float sr = 1.f / (1.f + __expf(-rt));
    out[off] = f2bf(sr * y);
  }
}

extern "C" void kernel_launch(void* const* d_in, const int* in_sizes, int n_in,
                              void* d_out, int out_size, void* d_ws, size_t ws_size,
                              hipStream_t stream) {
  const float* x    = (const float*)d_in[0];
  const float* tdec = (const float*)d_in[1];
  const float* tfir = (const float*)d_in[2];
  const float* tmk  = (const float*)d_in[3];
  const float* tmv  = (const float*)d_in[4];
  const float* tmr  = (const float*)d_in[5];
  const float* Wk   = (const float*)d_in[6];
  const float* Wv   = (const float*)d_in[7];
  const float* Wr   = (const float*)d_in[8];
  const float* Wo   = (const float*)d_in[9];

  const size_t M = (size_t)BB * TT;     // 16384
  char* ws = (char*)d_ws;
  unsigned short* mixbuf = (unsigned short*)ws; ws += M * CC * 2;       // 33.5 MB (also rwkv later)
  unsigned short* Wkb = (unsigned short*)ws;    ws += (size_t)CC * CC * 2;
  unsigned short* Wvb = (unsigned short*)ws;    ws += (size_t)CC * CC * 2;
  unsigned short* Wrb = (unsigned short*)ws;    ws += (size_t)CC * CC * 2;
  unsigned short* Wob = (unsigned short*)ws;    ws += (size_t)CC * CC * 2;
  float* kbuf = (float*)ws;                     ws += M * CC * 4;       // 64 MB
  float* vbuf = (float*)ws;                     ws += M * CC * 4;       // 64 MB
  unsigned short* rbuf = (unsigned short*)ws;   ws += M * CC * 2;       // 33.5 MB

  dim3 blk(256);
  const int gemm_grid = (int)((M / 64) * (CC / 64) / 4);  // 1024 blocks (4 waves each)

  cast_w_kernel<<<512, blk, 0, stream>>>(Wk, Wkb, CC * CC / 4);
  cast_w_kernel<<<512, blk, 0, stream>>>(Wv, Wvb, CC * CC / 4);
  cast_w_kernel<<<512, blk, 0, stream>>>(Wr, Wrb, CC * CC / 4);
  cast_w_kernel<<<512, blk, 0, stream>>>(Wo, Wob, CC * CC / 4);

  mix_cast_kernel<<<2048, blk, 0, stream>>>(x, tmk, mixbuf);
  gemm_bt<0><<<gemm_grid, blk, 0, stream>>>(mixbuf, Wkb, kbuf, (int)M, CC, CC);
  mix_cast_kernel<<<2048, blk, 0, stream>>>(x, tmv, mixbuf);
  gemm_bt<0><<<gemm_grid, blk, 0, stream>>>(mixbuf, Wvb, vbuf, (int)M, CC, CC);
  mix_cast_kernel<<<2048, blk, 0, stream>>>(x, tmr, mixbuf);
  gemm_bt<1><<<gemm_grid, blk, 0, stream>>>(mixbuf, Wrb, rbuf, (int)M, CC, CC);

  wkv_kernel<<<32, blk, 0, stream>>>(kbuf, vbuf, rbuf, tdec, tfir, mixbuf);

  gemm_bt<0><<<gemm_grid, blk, 0, stream>>>(mixbuf, Wob, d_out, (int)M, CC, CC);
}

// Round 2
// 649.895 us; speedup vs baseline: 1.9356x; 1.9356x over previous
//
#include <hip/hip_runtime.h>

#define BB 8
#define TT 2048
#define CC 1024
#define WKV_L 64
#define WKV_NCH (TT / WKV_L)   // 32 chunks

typedef __bf16 bf16x8_t __attribute__((ext_vector_type(8)));
typedef float f32x4_t __attribute__((ext_vector_type(4)));

__device__ __forceinline__ unsigned short f2bf(float f) {
  unsigned u = __float_as_uint(f);
  u += 0x7fffu + ((u >> 16) & 1u);   // round-to-nearest-even
  return (unsigned short)(u >> 16);
}
__device__ __forceinline__ float bf2f(unsigned short s) {
  return __uint_as_float(((unsigned)s) << 16);
}

// xk = x*tm + xshift*(1-tm), cast to bf16.  One row = (b,t); shift is t-1 within batch.
__global__ __launch_bounds__(256) void mix_cast_kernel(const float* __restrict__ x,
                                const float* __restrict__ tmix,
                                unsigned short* __restrict__ out) {
  const size_t total4 = (size_t)BB * TT * CC / 4;
  for (size_t i = (size_t)blockIdx.x * blockDim.x + threadIdx.x; i < total4;
       i += (size_t)gridDim.x * blockDim.x) {
    size_t e = i * 4;
    int c = (int)(e & (CC - 1));
    int t = (int)((e / CC) & (TT - 1));
    float4 xv = ((const float4*)x)[i];
    float4 xp = make_float4(0.f, 0.f, 0.f, 0.f);
    if (t > 0) xp = ((const float4*)x)[i - CC / 4];
    float4 tm = *(const float4*)(tmix + c);
    ushort4 o;
    o.x = f2bf(xv.x * tm.x + xp.x * (1.f - tm.x));
    o.y = f2bf(xv.y * tm.y + xp.y * (1.f - tm.y));
    o.z = f2bf(xv.z * tm.z + xp.z * (1.f - tm.z));
    o.w = f2bf(xv.w * tm.w + xp.w * (1.f - tm.w));
    *(ushort4*)(out + e) = o;
  }
}

__global__ __launch_bounds__(256) void cast_w_kernel(const float* __restrict__ w,
                              unsigned short* __restrict__ out, int n4) {
  for (int i = blockIdx.x * blockDim.x + threadIdx.x; i < n4;
       i += gridDim.x * blockDim.x) {
    float4 v = ((const float4*)w)[i];
    ushort4 o;
    o.x = f2bf(v.x); o.y = f2bf(v.y); o.z = f2bf(v.z); o.w = f2bf(v.w);
    ((ushort4*)out)[i] = o;
  }
}

// C[m,n] = sum_k A[m,k] * B[n,k]   (A:[M,K] bf16 row-major, B:[N,K] bf16 row-major)
// One wave computes a 64x64 output tile (4x4 grid of 16x16 MFMA frags).
template <int OUT_BF16>
__global__ __launch_bounds__(256) void gemm_bt(const unsigned short* __restrict__ A,
                        const unsigned short* __restrict__ Bm,
                        void* __restrict__ Cm, int M, int N, int K) {
  int wid = (blockIdx.x << 2) + (threadIdx.x >> 6);
  int lane = threadIdx.x & 63;
  int tiles_n = N >> 6;
  int tm = wid / tiles_n;
  int tn = wid - tm * tiles_n;
  if (tm >= (M >> 6)) return;
  int rr = lane & 15;          // fragment row (A) / row of B (=output col)
  int kg = (lane >> 4) << 3;   // k-subgroup offset: 8 contiguous k per lane group
  const unsigned short* Ap = A + (size_t)(tm * 64 + rr) * K + kg;
  const unsigned short* Bp = Bm + (size_t)(tn * 64 + rr) * K + kg;

  f32x4_t acc[4][4] = {};
  for (int k0 = 0; k0 < K; k0 += 32) {
    bf16x8_t a[4], b[4];
#pragma unroll
    for (int i = 0; i < 4; ++i) {
      a[i] = *(const bf16x8_t*)(Ap + (size_t)i * 16 * K + k0);
      b[i] = *(const bf16x8_t*)(Bp + (size_t)i * 16 * K + k0);
    }
#pragma unroll
    for (int i = 0; i < 4; ++i)
#pragma unroll
      for (int j = 0; j < 4; ++j)
        acc[i][j] = __builtin_amdgcn_mfma_f32_16x16x32_bf16(a[i], b[j], acc[i][j], 0, 0, 0);
  }

  // C/D layout (m89-verified): col = lane&15, row = (lane>>4)*4 + reg
  int orow0 = tm * 64 + ((lane >> 4) << 2);
  int ocol0 = tn * 64 + (lane & 15);
#pragma unroll
  for (int i = 0; i < 4; ++i)
#pragma unroll
    for (int j = 0; j < 4; ++j)
#pragma unroll
      for (int rg = 0; rg < 4; ++rg) {
        size_t row = (size_t)(orow0 + i * 16 + rg);
        size_t col = (size_t)(ocol0 + j * 16);
        if (OUT_BF16)
          ((unsigned short*)Cm)[row * N + col] = f2bf(acc[i][j][rg]);
        else
          ((float*)Cm)[row * N + col] = acc[i][j][rg];
      }
}

// ---- Chunk-parallel WKV scan --------------------------------------------
// Phase 1: per-(b,chunk,c) local summary (a,b,p): a*e^p = sum_{s in chunk}
// e^{k_s + w*(chunk_end-s)} v_s   (same stabilized update as reference,
// starting from the empty state).
__global__ __launch_bounds__(256) void wkv_phase1(const float* __restrict__ k,
                           const float* __restrict__ v,
                           const float* __restrict__ wdec,
                           float* __restrict__ Sa, float* __restrict__ Sb,
                           float* __restrict__ Sp) {
  int idx = blockIdx.x * blockDim.x + threadIdx.x;  // (b*NCH + j)*CC + c
  int c = idx & (CC - 1);
  int bj = idx >> 10;
  int j = bj % WKV_NCH;
  int b = bj / WKV_NCH;
  float w = -__expf(wdec[c]);
  size_t base = (size_t)b * TT * CC + (size_t)j * WKV_L * CC + c;
  float aa = 0.f, bb = 0.f, pp = -1e38f;
  for (int t = 0; t < WKV_L; ++t) {
    size_t off = base + (size_t)t * CC;
    float kt = k[off];
    float vt = v[off];
    float ww2 = pp + w;
    float q2 = fmaxf(ww2, kt);
    float f1 = __expf(ww2 - q2);
    float f2 = __expf(kt - q2);
    aa = fmaf(f1, aa, f2 * vt);
    bb = fmaf(f1, bb, f2);
    pp = q2;
  }
  Sa[idx] = aa; Sb[idx] = bb; Sp[idx] = pp;
}

// Phase 2: serial scan over chunk summaries -> incoming state per chunk.
__global__ __launch_bounds__(256) void wkv_phase2(const float* __restrict__ wdec,
                           const float* __restrict__ Sa, const float* __restrict__ Sb,
                           const float* __restrict__ Sp,
                           float* __restrict__ Ia, float* __restrict__ Ib,
                           float* __restrict__ Ip) {
  int idx = blockIdx.x * blockDim.x + threadIdx.x;  // b*CC + c
  if (idx >= BB * CC) return;
  int c = idx & (CC - 1);
  int b = idx >> 10;
  float wL = -__expf(wdec[c]) * (float)WKV_L;
  float aa = 0.f, bb = 0.f, pp = -1e38f;
  for (int j = 0; j < WKV_NCH; ++j) {
    size_t s = (size_t)(b * WKV_NCH + j) * CC + c;
    Ia[s] = aa; Ib[s] = bb; Ip[s] = pp;
    float pd = pp + wL;
    float ps = Sp[s];
    float q = fmaxf(pd, ps);
    float e1 = __expf(pd - q);
    float e2 = __expf(ps - q);
    aa = fmaf(e1, aa, e2 * Sa[s]);
    bb = fmaf(e1, bb, e2 * Sb[s]);
    pp = q;
  }
}

// Phase 3: replay the exact reference recurrence within each chunk, seeded
// with the incoming state; emit sigmoid(r)*y in bf16.
__global__ __launch_bounds__(256) void wkv_phase3(const float* __restrict__ k,
                           const float* __restrict__ v,
                           const unsigned short* __restrict__ r,
                           const float* __restrict__ wdec,
                           const float* __restrict__ u,
                           const float* __restrict__ Ia, const float* __restrict__ Ib,
                           const float* __restrict__ Ip,
                           unsigned short* __restrict__ out) {
  int idx = blockIdx.x * blockDim.x + threadIdx.x;  // (b*NCH + j)*CC + c
  int c = idx & (CC - 1);
  int bj = idx >> 10;
  int j = bj % WKV_NCH;
  int b = bj / WKV_NCH;
  float w = -__expf(wdec[c]);
  float uu = u[c];
  float aa = Ia[idx], bb = Ib[idx], pp = Ip[idx];
  size_t base = (size_t)b * TT * CC + (size_t)j * WKV_L * CC + c;
  for (int t = 0; t < WKV_L; ++t) {
    size_t off = base + (size_t)t * CC;
    float kt = k[off];
    float vt = v[off];
    float ww = uu + kt;
    float q = fmaxf(pp, ww);
    float e1 = __expf(pp - q);
    float e2 = __expf(ww - q);
    float y = fmaf(e1, aa, e2 * vt) / fmaf(e1, bb, e2);
    float ww2 = pp + w;
    float q2 = fmaxf(ww2, kt);
    float f1 = __expf(ww2 - q2);
    float f2 = __expf(kt - q2);
    aa = fmaf(f1, aa, f2 * vt);
    bb = fmaf(f1, bb, f2);
    pp = q2;
    float rt = bf2f(r[off]);
    float sr = 1.f / (1.f + __expf(-rt));
    out[off] = f2bf(sr * y);
  }
}

extern "C" void kernel_launch(void* const* d_in, const int* in_sizes, int n_in,
                              void* d_out, int out_size, void* d_ws, size_t ws_size,
                              hipStream_t stream) {
  const float* x    = (const float*)d_in[0];
  const float* tdec = (const float*)d_in[1];
  const float* tfir = (const float*)d_in[2];
  const float* tmk  = (const float*)d_in[3];
  const float* tmv  = (const float*)d_in[4];
  const float* tmr  = (const float*)d_in[5];
  const float* Wk   = (const float*)d_in[6];
  const float* Wv   = (const float*)d_in[7];
  const float* Wr   = (const float*)d_in[8];
  const float* Wo   = (const float*)d_in[9];

  const size_t M = (size_t)BB * TT;     // 16384
  char* ws = (char*)d_ws;
  unsigned short* mixbuf = (unsigned short*)ws; ws += M * CC * 2;       // 33.5 MB (also rwkv later)
  unsigned short* Wkb = (unsigned short*)ws;    ws += (size_t)CC * CC * 2;
  unsigned short* Wvb = (unsigned short*)ws;    ws += (size_t)CC * CC * 2;
  unsigned short* Wrb = (unsigned short*)ws;    ws += (size_t)CC * CC * 2;
  unsigned short* Wob = (unsigned short*)ws;    ws += (size_t)CC * CC * 2;
  float* kbuf = (float*)ws;                     ws += M * CC * 4;       // 64 MB
  float* vbuf = (float*)ws;                     ws += M * CC * 4;       // 64 MB
  unsigned short* rbuf = (unsigned short*)ws;   ws += M * CC * 2;       // 33.5 MB
  const size_t nstate = (size_t)BB * WKV_NCH * CC;                      // 256K
  float* Sa = (float*)ws; ws += nstate * 4;
  float* Sb = (float*)ws; ws += nstate * 4;
  float* Sp = (float*)ws; ws += nstate * 4;
  float* Ia = (float*)ws; ws += nstate * 4;
  float* Ib = (float*)ws; ws += nstate * 4;
  float* Ip = (float*)ws; ws += nstate * 4;

  dim3 blk(256);
  const int gemm_grid = (int)((M / 64) * (CC / 64) / 4);  // 1024 blocks (4 waves each)
  const int wkv_grid = (int)(nstate / 256);               // 1024 blocks

  cast_w_kernel<<<512, blk, 0, stream>>>(Wk, Wkb, CC * CC / 4);
  cast_w_kernel<<<512, blk, 0, stream>>>(Wv, Wvb, CC * CC / 4);
  cast_w_kernel<<<512, blk, 0, stream>>>(Wr, Wrb, CC * CC / 4);
  cast_w_kernel<<<512, blk, 0, stream>>>(Wo, Wob, CC * CC / 4);

  mix_cast_kernel<<<2048, blk, 0, stream>>>(x, tmk, mixbuf);
  gemm_bt<0><<<gemm_grid, blk, 0, stream>>>(mixbuf, Wkb, kbuf, (int)M, CC, CC);
  mix_cast_kernel<<<2048, blk, 0, stream>>>(x, tmv, mixbuf);
  gemm_bt<0><<<gemm_grid, blk, 0, stream>>>(mixbuf, Wvb, vbuf, (int)M, CC, CC);
  mix_cast_kernel<<<2048, blk, 0, stream>>>(x, tmr, mixbuf);
  gemm_bt<1><<<gemm_grid, blk, 0, stream>>>(mixbuf, Wrb, rbuf, (int)M, CC, CC);

  wkv_phase1<<<wkv_grid, blk, 0, stream>>>(kbuf, vbuf, tdec, Sa, Sb, Sp);
  wkv_phase2<<<(BB * CC + 255) / 256, blk, 0, stream>>>(tdec, Sa, Sb, Sp, Ia, Ib, Ip);
  wkv_phase3<<<wkv_grid, blk, 0, stream>>>(kbuf, vbuf, rbuf, tdec, tfir, Ia, Ib, Ip, mixbuf);

  gemm_bt<0><<<gemm_grid, blk, 0, stream>>>(mixbuf, Wob, d_out, (int)M, CC, CC);
}

// Round 3
// 388.418 us; speedup vs baseline: 3.2386x; 1.6732x over previous
//
#include <hip/hip_runtime.h>

#define BB 8
#define TT 2048
#define CC 1024
#define WKV_L 64
#define WKV_NCH (TT / WKV_L)   // 32 chunks

typedef __bf16 bf16x8_t __attribute__((ext_vector_type(8)));
typedef float f32x4_t __attribute__((ext_vector_type(4)));

__device__ __forceinline__ unsigned short f2bf(float f) {
  unsigned u = __float_as_uint(f);
  u += 0x7fffu + ((u >> 16) & 1u);   // round-to-nearest-even
  return (unsigned short)(u >> 16);
}
__device__ __forceinline__ float bf2f(unsigned short s) {
  return __uint_as_float(((unsigned)s) << 16);
}

#define GLOAD16(gp, lp)                                                        \
  __builtin_amdgcn_global_load_lds(                                            \
      (const __attribute__((address_space(1))) void*)(gp),                     \
      (__attribute__((address_space(3))) void*)(lp), 16, 0, 0)

// ---- fused time-shift mix: writes xk, xv, xr bf16 in one pass over x ----
__global__ __launch_bounds__(256) void mix3_cast_kernel(
    const float* __restrict__ x, const float* __restrict__ tmk,
    const float* __restrict__ tmv, const float* __restrict__ tmr,
    unsigned short* __restrict__ xk, unsigned short* __restrict__ xv,
    unsigned short* __restrict__ xr) {
  const size_t total4 = (size_t)BB * TT * CC / 4;
  for (size_t i = (size_t)blockIdx.x * blockDim.x + threadIdx.x; i < total4;
       i += (size_t)gridDim.x * blockDim.x) {
    size_t e = i * 4;
    int c = (int)(e & (CC - 1));
    int t = (int)((e / CC) & (TT - 1));
    float4 xv4 = ((const float4*)x)[i];
    float4 xp = make_float4(0.f, 0.f, 0.f, 0.f);
    if (t > 0) xp = ((const float4*)x)[i - CC / 4];
    float4 mk = *(const float4*)(tmk + c);
    float4 mv = *(const float4*)(tmv + c);
    float4 mr = *(const float4*)(tmr + c);
    ushort4 ok, ov, orr;
    ok.x = f2bf(xv4.x * mk.x + xp.x * (1.f - mk.x));
    ok.y = f2bf(xv4.y * mk.y + xp.y * (1.f - mk.y));
    ok.z = f2bf(xv4.z * mk.z + xp.z * (1.f - mk.z));
    ok.w = f2bf(xv4.w * mk.w + xp.w * (1.f - mk.w));
    ov.x = f2bf(xv4.x * mv.x + xp.x * (1.f - mv.x));
    ov.y = f2bf(xv4.y * mv.y + xp.y * (1.f - mv.y));
    ov.z = f2bf(xv4.z * mv.z + xp.z * (1.f - mv.z));
    ov.w = f2bf(xv4.w * mv.w + xp.w * (1.f - mv.w));
    orr.x = f2bf(xv4.x * mr.x + xp.x * (1.f - mr.x));
    orr.y = f2bf(xv4.y * mr.y + xp.y * (1.f - mr.y));
    orr.z = f2bf(xv4.z * mr.z + xp.z * (1.f - mr.z));
    orr.w = f2bf(xv4.w * mr.w + xp.w * (1.f - mr.w));
    *(ushort4*)(xk + e) = ok;
    *(ushort4*)(xv + e) = ov;
    *(ushort4*)(xr + e) = orr;
  }
}

// single-output mix (fallback path when ws is small)
__global__ __launch_bounds__(256) void mix_cast_kernel(const float* __restrict__ x,
                                const float* __restrict__ tmix,
                                unsigned short* __restrict__ out) {
  const size_t total4 = (size_t)BB * TT * CC / 4;
  for (size_t i = (size_t)blockIdx.x * blockDim.x + threadIdx.x; i < total4;
       i += (size_t)gridDim.x * blockDim.x) {
    size_t e = i * 4;
    int c = (int)(e & (CC - 1));
    int t = (int)((e / CC) & (TT - 1));
    float4 xv = ((const float4*)x)[i];
    float4 xp = make_float4(0.f, 0.f, 0.f, 0.f);
    if (t > 0) xp = ((const float4*)x)[i - CC / 4];
    float4 tm = *(const float4*)(tmix + c);
    ushort4 o;
    o.x = f2bf(xv.x * tm.x + xp.x * (1.f - tm.x));
    o.y = f2bf(xv.y * tm.y + xp.y * (1.f - tm.y));
    o.z = f2bf(xv.z * tm.z + xp.z * (1.f - tm.z));
    o.w = f2bf(xv.w * tm.w + xp.w * (1.f - tm.w));
    *(ushort4*)(out + e) = o;
  }
}

__global__ __launch_bounds__(256) void cast_w_kernel(const float* __restrict__ w,
                              unsigned short* __restrict__ out, int n4) {
  for (int i = blockIdx.x * blockDim.x + threadIdx.x; i < n4;
       i += gridDim.x * blockDim.x) {
    float4 v = ((const float4*)w)[i];
    ushort4 o;
    o.x = f2bf(v.x); o.y = f2bf(v.y); o.z = f2bf(v.z); o.w = f2bf(v.w);
    ((ushort4*)out)[i] = o;
  }
}

// ---- m97-style LDS-staged GEMM ------------------------------------------
// C[m,n] = sum_k A[m,k]*B[n,k]; A:[M,K] bf16, B:[N,K] bf16, both row-major.
// Block = 256 threads (4 waves, 2x2 wave grid), tile 128x128, BK=64.
// global_load_lds width 16 with PRE-SWIZZLED global source column
// (slot ^= row&7 within each 128B LDS row); ds_read_b128 applies the same
// XOR -> ~2-way residual bank conflicts (free, m136).
#define BM 128
#define BN 128
#define BKK 64

template <int OUT_BF16>
__global__ __launch_bounds__(256) void gemm_tile(const unsigned short* __restrict__ A,
                          const unsigned short* __restrict__ Bm,
                          void* __restrict__ Cm, int M, int N, int K) {
  __shared__ unsigned short As[BM * BKK];  // 16 KB, row stride 128 B (8 slots of 16 B)
  __shared__ unsigned short Bs[BN * BKK];  // 16 KB

  const int tiles_n = N / BN;
  const int tm = blockIdx.x / tiles_n;
  const int tn = blockIdx.x % tiles_n;
  const int t = threadIdx.x;
  const int w = t >> 6;
  const int lane = t & 63;
  const int wr = w >> 1;   // wave row in 2x2 grid
  const int wc = w & 1;    // wave col

  // staging geometry: per round, 256 threads cover 32 rows x 64 cols (16B/lane)
  const int srow = (w << 3) + (lane >> 3);                  // 0..31
  const int scol = (((lane & 7) ^ (srow & 7)) << 3);        // pre-swizzled col (elems)
  const unsigned short* Ag = A + (size_t)(tm * BM + srow) * K + scol;
  const unsigned short* Bg = Bm + (size_t)(tn * BN + srow) * K + scol;
  unsigned short* Asl = &As[srow * BKK + scol];
  unsigned short* Bsl = &Bs[srow * BKK + scol];

  // fragment geometry
  const int fr = lane & 15;
  const int fk = lane >> 4;  // k sub-slot (8 elems each)
  const char* AsB = (const char*)As;
  const char* BsB = (const char*)Bs;

  f32x4_t acc[4][4] = {};

  for (int k0 = 0; k0 < K; k0 += BKK) {
#pragma unroll
    for (int i = 0; i < 4; ++i) {
      GLOAD16(Ag + (size_t)(i * 32) * K + k0, Asl + i * 32 * BKK);
      GLOAD16(Bg + (size_t)(i * 32) * K + k0, Bsl + i * 32 * BKK);
    }
    __syncthreads();  // drains vmcnt -> LDS tile ready

#pragma unroll
    for (int kk = 0; kk < 2; ++kk) {
      const int slotA = ((kk << 2) + fk) ^ (fr & 7);
      bf16x8_t a[4], b[4];
#pragma unroll
      for (int i = 0; i < 4; ++i) {
        int arow = wr * 64 + i * 16 + fr;
        a[i] = *(const bf16x8_t*)(AsB + arow * 128 + (slotA << 4));
        int brow = wc * 64 + i * 16 + fr;
        b[i] = *(const bf16x8_t*)(BsB + brow * 128 + (slotA << 4));
      }
#pragma unroll
      for (int i = 0; i < 4; ++i)
#pragma unroll
        for (int j = 0; j < 4; ++j)
          acc[i][j] = __builtin_amdgcn_mfma_f32_16x16x32_bf16(a[i], b[j], acc[i][j], 0, 0, 0);
    }
    __syncthreads();  // protect LDS before next stage
  }

  // C/D layout (m89-verified): col = lane&15, row = (lane>>4)*4 + reg
  int orow0 = tm * BM + wr * 64 + (fk << 2);
  int ocol0 = tn * BN + wc * 64 + fr;
#pragma unroll
  for (int i = 0; i < 4; ++i)
#pragma unroll
    for (int j = 0; j < 4; ++j)
#pragma unroll
      for (int rg = 0; rg < 4; ++rg) {
        size_t row = (size_t)(orow0 + i * 16 + rg);
        size_t col = (size_t)(ocol0 + j * 16);
        if (OUT_BF16)
          ((unsigned short*)Cm)[row * N + col] = f2bf(acc[i][j][rg]);
        else
          ((float*)Cm)[row * N + col] = acc[i][j][rg];
      }
}

// ---- Chunk-parallel WKV scan --------------------------------------------
__global__ __launch_bounds__(256) void wkv_phase1(const float* __restrict__ k,
                           const float* __restrict__ v,
                           const float* __restrict__ wdec,
                           float* __restrict__ Sa, float* __restrict__ Sb,
                           float* __restrict__ Sp) {
  int idx = blockIdx.x * blockDim.x + threadIdx.x;
  int c = idx & (CC - 1);
  int bj = idx >> 10;
  int j = bj % WKV_NCH;
  int b = bj / WKV_NCH;
  float w = -__expf(wdec[c]);
  size_t base = (size_t)b * TT * CC + (size_t)j * WKV_L * CC + c;
  float aa = 0.f, bb = 0.f, pp = -1e38f;
  for (int t = 0; t < WKV_L; ++t) {
    size_t off = base + (size_t)t * CC;
    float kt = k[off];
    float vt = v[off];
    float ww2 = pp + w;
    float q2 = fmaxf(ww2, kt);
    float f1 = __expf(ww2 - q2);
    float f2 = __expf(kt - q2);
    aa = fmaf(f1, aa, f2 * vt);
    bb = fmaf(f1, bb, f2);
    pp = q2;
  }
  Sa[idx] = aa; Sb[idx] = bb; Sp[idx] = pp;
}

__global__ __launch_bounds__(256) void wkv_phase2(const float* __restrict__ wdec,
                           const float* __restrict__ Sa, const float* __restrict__ Sb,
                           const float* __restrict__ Sp,
                           float* __restrict__ Ia, float* __restrict__ Ib,
                           float* __restrict__ Ip) {
  int idx = blockIdx.x * blockDim.x + threadIdx.x;
  if (idx >= BB * CC) return;
  int c = idx & (CC - 1);
  int b = idx >> 10;
  float wL = -__expf(wdec[c]) * (float)WKV_L;
  float aa = 0.f, bb = 0.f, pp = -1e38f;
  for (int j = 0; j < WKV_NCH; ++j) {
    size_t s = (size_t)(b * WKV_NCH + j) * CC + c;
    Ia[s] = aa; Ib[s] = bb; Ip[s] = pp;
    float pd = pp + wL;
    float ps = Sp[s];
    float q = fmaxf(pd, ps);
    float e1 = __expf(pd - q);
    float e2 = __expf(ps - q);
    aa = fmaf(e1, aa, e2 * Sa[s]);
    bb = fmaf(e1, bb, e2 * Sb[s]);
    pp = q;
  }
}

__global__ __launch_bounds__(256) void wkv_phase3(const float* __restrict__ k,
                           const float* __restrict__ v,
                           const unsigned short* __restrict__ r,
                           const float* __restrict__ wdec,
                           const float* __restrict__ u,
                           const float* __restrict__ Ia, const float* __restrict__ Ib,
                           const float* __restrict__ Ip,
                           unsigned short* __restrict__ out) {
  int idx = blockIdx.x * blockDim.x + threadIdx.x;
  int c = idx & (CC - 1);
  int bj = idx >> 10;
  int j = bj % WKV_NCH;
  int b = bj / WKV_NCH;
  float w = -__expf(wdec[c]);
  float uu = u[c];
  float aa = Ia[idx], bb = Ib[idx], pp = Ip[idx];
  size_t base = (size_t)b * TT * CC + (size_t)j * WKV_L * CC + c;
  for (int t = 0; t < WKV_L; ++t) {
    size_t off = base + (size_t)t * CC;
    float kt = k[off];
    float vt = v[off];
    float ww = uu + kt;
    float q = fmaxf(pp, ww);
    float e1 = __expf(pp - q);
    float e2 = __expf(ww - q);
    float y = fmaf(e1, aa, e2 * vt) / fmaf(e1, bb, e2);
    float ww2 = pp + w;
    float q2 = fmaxf(ww2, kt);
    float f1 = __expf(ww2 - q2);
    float f2 = __expf(kt - q2);
    aa = fmaf(f1, aa, f2 * vt);
    bb = fmaf(f1, bb, f2);
    pp = q2;
    float rt = bf2f(r[off]);
    float sr = 1.f / (1.f + __expf(-rt));
    out[off] = f2bf(sr * y);
  }
}

extern "C" void kernel_launch(void* const* d_in, const int* in_sizes, int n_in,
                              void* d_out, int out_size, void* d_ws, size_t ws_size,
                              hipStream_t stream) {
  const float* x    = (const float*)d_in[0];
  const float* tdec = (const float*)d_in[1];
  const float* tfir = (const float*)d_in[2];
  const float* tmk  = (const float*)d_in[3];
  const float* tmv  = (const float*)d_in[4];
  const float* tmr  = (const float*)d_in[5];
  const float* Wk   = (const float*)d_in[6];
  const float* Wv   = (const float*)d_in[7];
  const float* Wr   = (const float*)d_in[8];
  const float* Wo   = (const float*)d_in[9];

  const size_t M = (size_t)BB * TT;     // 16384
  const size_t mixbytes = M * CC * 2;   // 33.5 MB
  const size_t wbytes = (size_t)CC * CC * 2;
  const size_t nstate = (size_t)BB * WKV_NCH * CC;

  // big layout: 3 separate mix buffers (fused mix); small: 1 shared buffer
  const size_t need_big = 3 * mixbytes + 4 * wbytes + 2 * (M * CC * 4) +
                          mixbytes + 6 * nstate * 4;
  const bool big = ws_size >= need_big;

  char* ws = (char*)d_ws;
  unsigned short* xkb = (unsigned short*)ws; ws += mixbytes;
  unsigned short* xvb = xkb, *xrb = xkb;
  if (big) {
    xvb = (unsigned short*)ws; ws += mixbytes;
    xrb = (unsigned short*)ws; ws += mixbytes;
  }
  unsigned short* Wkb = (unsigned short*)ws; ws += wbytes;
  unsigned short* Wvb = (unsigned short*)ws; ws += wbytes;
  unsigned short* Wrb = (unsigned short*)ws; ws += wbytes;
  unsigned short* Wob = (unsigned short*)ws; ws += wbytes;
  float* kbuf = (float*)ws;                  ws += M * CC * 4;
  float* vbuf = (float*)ws;                  ws += M * CC * 4;
  unsigned short* rbuf = (unsigned short*)ws; ws += mixbytes;
  float* Sa = (float*)ws; ws += nstate * 4;
  float* Sb = (float*)ws; ws += nstate * 4;
  float* Sp = (float*)ws; ws += nstate * 4;
  float* Ia = (float*)ws; ws += nstate * 4;
  float* Ib = (float*)ws; ws += nstate * 4;
  float* Ip = (float*)ws; ws += nstate * 4;

  dim3 blk(256);
  const int gemm_grid = (int)((M / BM) * (CC / BN));      // 1024 blocks
  const int wkv_grid = (int)(nstate / 256);               // 1024 blocks

  cast_w_kernel<<<512, blk, 0, stream>>>(Wk, Wkb, CC * CC / 4);
  cast_w_kernel<<<512, blk, 0, stream>>>(Wv, Wvb, CC * CC / 4);
  cast_w_kernel<<<512, blk, 0, stream>>>(Wr, Wrb, CC * CC / 4);
  cast_w_kernel<<<512, blk, 0, stream>>>(Wo, Wob, CC * CC / 4);

  if (big) {
    mix3_cast_kernel<<<2048, blk, 0, stream>>>(x, tmk, tmv, tmr, xkb, xvb, xrb);
    gemm_tile<0><<<gemm_grid, blk, 0, stream>>>(xkb, Wkb, kbuf, (int)M, CC, CC);
    gemm_tile<0><<<gemm_grid, blk, 0, stream>>>(xvb, Wvb, vbuf, (int)M, CC, CC);
    gemm_tile<1><<<gemm_grid, blk, 0, stream>>>(xrb, Wrb, rbuf, (int)M, CC, CC);
  } else {
    mix_cast_kernel<<<2048, blk, 0, stream>>>(x, tmk, xkb);
    gemm_tile<0><<<gemm_grid, blk, 0, stream>>>(xkb, Wkb, kbuf, (int)M, CC, CC);
    mix_cast_kernel<<<2048, blk, 0, stream>>>(x, tmv, xkb);
    gemm_tile<0><<<gemm_grid, blk, 0, stream>>>(xkb, Wvb, vbuf, (int)M, CC, CC);
    mix_cast_kernel<<<2048, blk, 0, stream>>>(x, tmr, xkb);
    gemm_tile<1><<<gemm_grid, blk, 0, stream>>>(xkb, Wrb, rbuf, (int)M, CC, CC);
  }

  wkv_phase1<<<wkv_grid, blk, 0, stream>>>(kbuf, vbuf, tdec, Sa, Sb, Sp);
  wkv_phase2<<<(BB * CC + 255) / 256, blk, 0, stream>>>(tdec, Sa, Sb, Sp, Ia, Ib, Ip);
  wkv_phase3<<<wkv_grid, blk, 0, stream>>>(kbuf, vbuf, rbuf, tdec, tfir, Ia, Ib, Ip, xkb);

  gemm_tile<0><<<gemm_grid, blk, 0, stream>>>(xkb, Wob, d_out, (int)M, CC, CC);
}

// Round 4
// 317.865 us; speedup vs baseline: 3.9574x; 1.2220x over previous
//
#include <hip/hip_runtime.h>

#define BB 8
#define TT 2048
#define CC 1024
#define WKV_L 64
#define WKV_NCH (TT / WKV_L)   // 32 chunks

typedef __bf16 bf16x8_t __attribute__((ext_vector_type(8)));
typedef float f32x4_t __attribute__((ext_vector_type(4)));

__device__ __forceinline__ unsigned short f2bf(float f) {
  unsigned u = __float_as_uint(f);
  u += 0x7fffu + ((u >> 16) & 1u);   // round-to-nearest-even
  return (unsigned short)(u >> 16);
}
__device__ __forceinline__ float bf2f(unsigned short s) {
  return __uint_as_float(((unsigned)s) << 16);
}

#define GLOAD16(gp, lp)                                                        \
  __builtin_amdgcn_global_load_lds(                                            \
      (const __attribute__((address_space(1))) void*)(gp),                     \
      (__attribute__((address_space(3))) void*)(lp), 16, 0, 0)

// ---- fused time-shift mix: writes xk, xv, xr bf16 in one pass over x ----
__global__ __launch_bounds__(256) void mix3_cast_kernel(
    const float* __restrict__ x, const float* __restrict__ tmk,
    const float* __restrict__ tmv, const float* __restrict__ tmr,
    unsigned short* __restrict__ xk, unsigned short* __restrict__ xv,
    unsigned short* __restrict__ xr) {
  const size_t total4 = (size_t)BB * TT * CC / 4;
  for (size_t i = (size_t)blockIdx.x * blockDim.x + threadIdx.x; i < total4;
       i += (size_t)gridDim.x * blockDim.x) {
    size_t e = i * 4;
    int c = (int)(e & (CC - 1));
    int t = (int)((e / CC) & (TT - 1));
    float4 xv4 = ((const float4*)x)[i];
    float4 xp = make_float4(0.f, 0.f, 0.f, 0.f);
    if (t > 0) xp = ((const float4*)x)[i - CC / 4];
    float4 mk = *(const float4*)(tmk + c);
    float4 mv = *(const float4*)(tmv + c);
    float4 mr = *(const float4*)(tmr + c);
    ushort4 ok, ov, orr;
    ok.x = f2bf(xv4.x * mk.x + xp.x * (1.f - mk.x));
    ok.y = f2bf(xv4.y * mk.y + xp.y * (1.f - mk.y));
    ok.z = f2bf(xv4.z * mk.z + xp.z * (1.f - mk.z));
    ok.w = f2bf(xv4.w * mk.w + xp.w * (1.f - mk.w));
    ov.x = f2bf(xv4.x * mv.x + xp.x * (1.f - mv.x));
    ov.y = f2bf(xv4.y * mv.y + xp.y * (1.f - mv.y));
    ov.z = f2bf(xv4.z * mv.z + xp.z * (1.f - mv.z));
    ov.w = f2bf(xv4.w * mv.w + xp.w * (1.f - mv.w));
    orr.x = f2bf(xv4.x * mr.x + xp.x * (1.f - mr.x));
    orr.y = f2bf(xv4.y * mr.y + xp.y * (1.f - mr.y));
    orr.z = f2bf(xv4.z * mr.z + xp.z * (1.f - mr.z));
    orr.w = f2bf(xv4.w * mr.w + xp.w * (1.f - mr.w));
    *(ushort4*)(xk + e) = ok;
    *(ushort4*)(xv + e) = ov;
    *(ushort4*)(xr + e) = orr;
  }
}

// single-output mix (fallback path when ws is small)
__global__ __launch_bounds__(256) void mix_cast_kernel(const float* __restrict__ x,
                                const float* __restrict__ tmix,
                                unsigned short* __restrict__ out) {
  const size_t total4 = (size_t)BB * TT * CC / 4;
  for (size_t i = (size_t)blockIdx.x * blockDim.x + threadIdx.x; i < total4;
       i += (size_t)gridDim.x * blockDim.x) {
    size_t e = i * 4;
    int c = (int)(e & (CC - 1));
    int t = (int)((e / CC) & (TT - 1));
    float4 xv = ((const float4*)x)[i];
    float4 xp = make_float4(0.f, 0.f, 0.f, 0.f);
    if (t > 0) xp = ((const float4*)x)[i - CC / 4];
    float4 tm = *(const float4*)(tmix + c);
    ushort4 o;
    o.x = f2bf(xv.x * tm.x + xp.x * (1.f - tm.x));
    o.y = f2bf(xv.y * tm.y + xp.y * (1.f - tm.y));
    o.z = f2bf(xv.z * tm.z + xp.z * (1.f - tm.z));
    o.w = f2bf(xv.w * tm.w + xp.w * (1.f - tm.w));
    *(ushort4*)(out + e) = o;
  }
}

// all 4 weight casts in one launch; outputs are contiguous regions.
__global__ __launch_bounds__(256) void cast_w4_kernel(
    const float* __restrict__ w0, const float* __restrict__ w1,
    const float* __restrict__ w2, const float* __restrict__ w3,
    unsigned short* __restrict__ o0, unsigned short* __restrict__ o1,
    unsigned short* __restrict__ o2, unsigned short* __restrict__ o3) {
  const int n4 = CC * CC / 4;   // per weight
  for (int i = blockIdx.x * blockDim.x + threadIdx.x; i < 4 * n4;
       i += gridDim.x * blockDim.x) {
    int sel = i / n4;
    int j = i - sel * n4;
    const float* w = sel == 0 ? w0 : sel == 1 ? w1 : sel == 2 ? w2 : w3;
    unsigned short* o = sel == 0 ? o0 : sel == 1 ? o1 : sel == 2 ? o2 : o3;
    float4 v = ((const float4*)w)[j];
    ushort4 u;
    u.x = f2bf(v.x); u.y = f2bf(v.y); u.z = f2bf(v.z); u.w = f2bf(v.w);
    ((ushort4*)o)[j] = u;
  }
}

// ---- m97-style LDS-staged GEMM core -------------------------------------
// C[m,n] = sum_k A[m,k]*B[n,k]; 128x128 tile, BK=64, 4 waves.
#define BM 128
#define BN 128
#define BKK 64
#define TILES_N (CC / BN)        // 8
#define TM_TILES ((BB * TT) / BM)  // 128

// body shared by both GEMM kernels; A,B bf16 row-major [rows,K]
template <typename EPI>
__device__ __forceinline__ void gemm_body(const unsigned short* __restrict__ A,
                                          const unsigned short* __restrict__ Bm,
                                          int tm, int tn, int K, EPI epi) {
  __shared__ unsigned short As[BM * BKK];  // 16 KB
  __shared__ unsigned short Bs[BN * BKK];  // 16 KB
  const int t = threadIdx.x;
  const int w = t >> 6;
  const int lane = t & 63;
  const int wr = w >> 1;
  const int wc = w & 1;

  const int srow = (w << 3) + (lane >> 3);                  // 0..31
  const int scol = (((lane & 7) ^ (srow & 7)) << 3);        // pre-swizzled col
  const unsigned short* Ag = A + (size_t)(tm * BM + srow) * K + scol;
  const unsigned short* Bg = Bm + (size_t)(tn * BN + srow) * K + scol;
  unsigned short* Asl = &As[srow * BKK + scol];
  unsigned short* Bsl = &Bs[srow * BKK + scol];

  const int fr = lane & 15;
  const int fk = lane >> 4;
  const char* AsB = (const char*)As;
  const char* BsB = (const char*)Bs;

  f32x4_t acc[4][4] = {};

  for (int k0 = 0; k0 < K; k0 += BKK) {
#pragma unroll
    for (int i = 0; i < 4; ++i) {
      GLOAD16(Ag + (size_t)(i * 32) * K + k0, Asl + i * 32 * BKK);
      GLOAD16(Bg + (size_t)(i * 32) * K + k0, Bsl + i * 32 * BKK);
    }
    __syncthreads();

#pragma unroll
    for (int kk = 0; kk < 2; ++kk) {
      const int slotA = ((kk << 2) + fk) ^ (fr & 7);
      bf16x8_t a[4], b[4];
#pragma unroll
      for (int i = 0; i < 4; ++i) {
        int arow = wr * 64 + i * 16 + fr;
        a[i] = *(const bf16x8_t*)(AsB + arow * 128 + (slotA << 4));
        int brow = wc * 64 + i * 16 + fr;
        b[i] = *(const bf16x8_t*)(BsB + brow * 128 + (slotA << 4));
      }
#pragma unroll
      for (int i = 0; i < 4; ++i)
#pragma unroll
        for (int j = 0; j < 4; ++j)
          acc[i][j] = __builtin_amdgcn_mfma_f32_16x16x32_bf16(a[i], b[j], acc[i][j], 0, 0, 0);
    }
    __syncthreads();
  }

  // C/D layout: col = lane&15, row = (lane>>4)*4 + reg
  int orow0 = tm * BM + wr * 64 + (fk << 2);
  int ocol0 = tn * BN + wc * 64 + fr;
#pragma unroll
  for (int i = 0; i < 4; ++i)
#pragma unroll
    for (int j = 0; j < 4; ++j)
#pragma unroll
      for (int rg = 0; rg < 4; ++rg)
        epi((size_t)(orow0 + i * 16 + rg) * CC + (size_t)(ocol0 + j * 16),
            acc[i][j][rg]);
}

// merged k/v/r projection GEMM: 3072 blocks, XCD-swizzled globally.
__global__ __launch_bounds__(256) void gemm_kvr(
    const unsigned short* __restrict__ xk, const unsigned short* __restrict__ xv,
    const unsigned short* __restrict__ xr, const unsigned short* __restrict__ Wk,
    const unsigned short* __restrict__ Wv, const unsigned short* __restrict__ Wr,
    float* __restrict__ kout, unsigned short* __restrict__ vout,
    unsigned short* __restrict__ rout) {
  const int nwg = 3 * TM_TILES * TILES_N;   // 3072
  const int q = nwg >> 3;                   // 384
  int orig = blockIdx.x;
  int wg = (orig & 7) * q + (orig >> 3);
  int which = wg >> 10;                     // /1024
  int rr = wg & 1023;
  int tm = rr >> 3;                         // tn-fast within XCD chunk
  int tn = rr & 7;
  const unsigned short* A = which == 0 ? xk : which == 1 ? xv : xr;
  const unsigned short* Bm = which == 0 ? Wk : which == 1 ? Wv : Wr;
  if (which == 0) {
    gemm_body(A, Bm, tm, tn, CC, [&](size_t off, float val) { kout[off] = val; });
  } else {
    unsigned short* o = which == 1 ? vout : rout;
    gemm_body(A, Bm, tm, tn, CC, [&](size_t off, float val) { o[off] = f2bf(val); });
  }
}

// single GEMM (XCD-swizzled), fp32 or bf16 out
template <int OUT_BF16>
__global__ __launch_bounds__(256) void gemm_tile(const unsigned short* __restrict__ A,
                          const unsigned short* __restrict__ Bm,
                          void* __restrict__ Cm) {
  const int nwg = TM_TILES * TILES_N;       // 1024
  const int q = nwg >> 3;                   // 128
  int orig = blockIdx.x;
  int wg = (orig & 7) * q + (orig >> 3);
  int tm = wg >> 3;
  int tn = wg & 7;
  if (OUT_BF16)
    gemm_body(A, Bm, tm, tn, CC,
              [&](size_t off, float val) { ((unsigned short*)Cm)[off] = f2bf(val); });
  else
    gemm_body(A, Bm, tm, tn, CC,
              [&](size_t off, float val) { ((float*)Cm)[off] = val; });
}

// ---- Chunk-parallel WKV scan --------------------------------------------
__global__ __launch_bounds__(256) void wkv_phase1(const float* __restrict__ k,
                           const unsigned short* __restrict__ v,
                           const float* __restrict__ wdec,
                           float* __restrict__ Sa, float* __restrict__ Sb,
                           float* __restrict__ Sp) {
  int idx = blockIdx.x * blockDim.x + threadIdx.x;
  int c = idx & (CC - 1);
  int bj = idx >> 10;
  int j = bj % WKV_NCH;
  int b = bj / WKV_NCH;
  float w = -__expf(wdec[c]);
  size_t base = (size_t)b * TT * CC + (size_t)j * WKV_L * CC + c;
  float aa = 0.f, bb = 0.f, pp = -1e38f;
  for (int t = 0; t < WKV_L; ++t) {
    size_t off = base + (size_t)t * CC;
    float kt = k[off];
    float vt = bf2f(v[off]);
    float ww2 = pp + w;
    float q2 = fmaxf(ww2, kt);
    float f1 = __expf(ww2 - q2);
    float f2 = __expf(kt - q2);
    aa = fmaf(f1, aa, f2 * vt);
    bb = fmaf(f1, bb, f2);
    pp = q2;
  }
  Sa[idx] = aa; Sb[idx] = bb; Sp[idx] = pp;
}

__global__ __launch_bounds__(256) void wkv_phase2(const float* __restrict__ wdec,
                           const float* __restrict__ Sa, const float* __restrict__ Sb,
                           const float* __restrict__ Sp,
                           float* __restrict__ Ia, float* __restrict__ Ib,
                           float* __restrict__ Ip) {
  int idx = blockIdx.x * blockDim.x + threadIdx.x;
  if (idx >= BB * CC) return;
  int c = idx & (CC - 1);
  int b = idx >> 10;
  float wL = -__expf(wdec[c]) * (float)WKV_L;
  float aa = 0.f, bb = 0.f, pp = -1e38f;
  for (int j = 0; j < WKV_NCH; ++j) {
    size_t s = (size_t)(b * WKV_NCH + j) * CC + c;
    Ia[s] = aa; Ib[s] = bb; Ip[s] = pp;
    float pd = pp + wL;
    float ps = Sp[s];
    float q = fmaxf(pd, ps);
    float e1 = __expf(pd - q);
    float e2 = __expf(ps - q);
    aa = fmaf(e1, aa, e2 * Sa[s]);
    bb = fmaf(e1, bb, e2 * Sb[s]);
    pp = q;
  }
}

__global__ __launch_bounds__(256) void wkv_phase3(const float* __restrict__ k,
                           const unsigned short* __restrict__ v,
                           const unsigned short* __restrict__ r,
                           const float* __restrict__ wdec,
                           const float* __restrict__ u,
                           const float* __restrict__ Ia, const float* __restrict__ Ib,
                           const float* __restrict__ Ip,
                           unsigned short* __restrict__ out) {
  int idx = blockIdx.x * blockDim.x + threadIdx.x;
  int c = idx & (CC - 1);
  int bj = idx >> 10;
  int j = bj % WKV_NCH;
  int b = bj / WKV_NCH;
  float w = -__expf(wdec[c]);
  float uu = u[c];
  float aa = Ia[idx], bb = Ib[idx], pp = Ip[idx];
  size_t base = (size_t)b * TT * CC + (size_t)j * WKV_L * CC + c;
  for (int t = 0; t < WKV_L; ++t) {
    size_t off = base + (size_t)t * CC;
    float kt = k[off];
    float vt = bf2f(v[off]);
    float ww = uu + kt;
    float q = fmaxf(pp, ww);
    float e1 = __expf(pp - q);
    float e2 = __expf(ww - q);
    float y = fmaf(e1, aa, e2 * vt) / fmaf(e1, bb, e2);
    float ww2 = pp + w;
    float q2 = fmaxf(ww2, kt);
    float f1 = __expf(ww2 - q2);
    float f2 = __expf(kt - q2);
    aa = fmaf(f1, aa, f2 * vt);
    bb = fmaf(f1, bb, f2);
    pp = q2;
    float rt = bf2f(r[off]);
    float sr = 1.f / (1.f + __expf(-rt));
    out[off] = f2bf(sr * y);
  }
}

extern "C" void kernel_launch(void* const* d_in, const int* in_sizes, int n_in,
                              void* d_out, int out_size, void* d_ws, size_t ws_size,
                              hipStream_t stream) {
  const float* x    = (const float*)d_in[0];
  const float* tdec = (const float*)d_in[1];
  const float* tfir = (const float*)d_in[2];
  const float* tmk  = (const float*)d_in[3];
  const float* tmv  = (const float*)d_in[4];
  const float* tmr  = (const float*)d_in[5];
  const float* Wk   = (const float*)d_in[6];
  const float* Wv   = (const float*)d_in[7];
  const float* Wr   = (const float*)d_in[8];
  const float* Wo   = (const float*)d_in[9];

  const size_t M = (size_t)BB * TT;     // 16384
  const size_t mixbytes = M * CC * 2;   // 33.5 MB
  const size_t wbytes = (size_t)CC * CC * 2;
  const size_t nstate = (size_t)BB * WKV_NCH * CC;

  const size_t need_big = 3 * mixbytes + 4 * wbytes + (M * CC * 4) + 2 * mixbytes +
                          mixbytes + 6 * nstate * 4;
  const bool big = ws_size >= need_big;

  char* ws = (char*)d_ws;
  unsigned short* xkb = (unsigned short*)ws; ws += mixbytes;
  unsigned short* xvb = xkb, *xrb = xkb;
  if (big) {
    xvb = (unsigned short*)ws; ws += mixbytes;
    xrb = (unsigned short*)ws; ws += mixbytes;
  }
  unsigned short* Wkb = (unsigned short*)ws; ws += wbytes;
  unsigned short* Wvb = (unsigned short*)ws; ws += wbytes;
  unsigned short* Wrb = (unsigned short*)ws; ws += wbytes;
  unsigned short* Wob = (unsigned short*)ws; ws += wbytes;
  float* kbuf = (float*)ws;                   ws += M * CC * 4;
  unsigned short* vbuf = (unsigned short*)ws; ws += mixbytes;
  unsigned short* rbuf = (unsigned short*)ws; ws += mixbytes;
  float* Sa = (float*)ws; ws += nstate * 4;
  float* Sb = (float*)ws; ws += nstate * 4;
  float* Sp = (float*)ws; ws += nstate * 4;
  float* Ia = (float*)ws; ws += nstate * 4;
  float* Ib = (float*)ws; ws += nstate * 4;
  float* Ip = (float*)ws; ws += nstate * 4;

  dim3 blk(256);
  const int gemm_grid = (int)((M / BM) * (CC / BN));      // 1024
  const int wkv_grid = (int)(nstate / 256);               // 1024

  cast_w4_kernel<<<1024, blk, 0, stream>>>(Wk, Wv, Wr, Wo, Wkb, Wvb, Wrb, Wob);

  if (big) {
    mix3_cast_kernel<<<2048, blk, 0, stream>>>(x, tmk, tmv, tmr, xkb, xvb, xrb);
    gemm_kvr<<<3 * gemm_grid, blk, 0, stream>>>(xkb, xvb, xrb, Wkb, Wvb, Wrb,
                                                kbuf, vbuf, rbuf);
  } else {
    mix_cast_kernel<<<2048, blk, 0, stream>>>(x, tmk, xkb);
    gemm_tile<0><<<gemm_grid, blk, 0, stream>>>(xkb, Wkb, kbuf);
    mix_cast_kernel<<<2048, blk, 0, stream>>>(x, tmv, xkb);
    gemm_tile<1><<<gemm_grid, blk, 0, stream>>>(xkb, Wvb, vbuf);
    mix_cast_kernel<<<2048, blk, 0, stream>>>(x, tmr, xkb);
    gemm_tile<1><<<gemm_grid, blk, 0, stream>>>(xkb, Wrb, rbuf);
  }

  wkv_phase1<<<wkv_grid, blk, 0, stream>>>(kbuf, vbuf, tdec, Sa, Sb, Sp);
  wkv_phase2<<<(BB * CC + 255) / 256, blk, 0, stream>>>(tdec, Sa, Sb, Sp, Ia, Ib, Ip);
  wkv_phase3<<<wkv_grid, blk, 0, stream>>>(kbuf, vbuf, rbuf, tdec, tfir, Ia, Ib, Ip, xkb);

  gemm_tile<0><<<gemm_grid, blk, 0, stream>>>(xkb, Wob, d_out);
}

// Round 6
// 291.739 us; speedup vs baseline: 4.3119x; 1.0896x over previous
//
#include <hip/hip_runtime.h>

#define BB 8
#define TT 2048
#define CC 1024
#define WKV_L 64
#define WKV_NCH (TT / WKV_L)   // 32 chunks

typedef __bf16 bf16x8_t __attribute__((ext_vector_type(8)));
typedef float f32x4_t __attribute__((ext_vector_type(4)));

__device__ __forceinline__ unsigned short f2bf(float f) {
  unsigned u = __float_as_uint(f);
  u += 0x7fffu + ((u >> 16) & 1u);   // round-to-nearest-even
  return (unsigned short)(u >> 16);
}
__device__ __forceinline__ float bf2f(unsigned short s) {
  return __uint_as_float(((unsigned)s) << 16);
}

#define GLOAD16(gp, lp)                                                        \
  __builtin_amdgcn_global_load_lds(                                            \
      (const __attribute__((address_space(1))) void*)(gp),                     \
      (__attribute__((address_space(3))) void*)(lp), 16, 0, 0)

// ---- fused time-shift mix: writes xk, xv, xr bf16 in one pass over x ----
__global__ __launch_bounds__(256) void mix3_cast_kernel(
    const float* __restrict__ x, const float* __restrict__ tmk,
    const float* __restrict__ tmv, const float* __restrict__ tmr,
    unsigned short* __restrict__ xk, unsigned short* __restrict__ xv,
    unsigned short* __restrict__ xr) {
  const size_t total4 = (size_t)BB * TT * CC / 4;
  for (size_t i = (size_t)blockIdx.x * blockDim.x + threadIdx.x; i < total4;
       i += (size_t)gridDim.x * blockDim.x) {
    size_t e = i * 4;
    int c = (int)(e & (CC - 1));
    int t = (int)((e / CC) & (TT - 1));
    float4 xv4 = ((const float4*)x)[i];
    float4 xp = make_float4(0.f, 0.f, 0.f, 0.f);
    if (t > 0) xp = ((const float4*)x)[i - CC / 4];
    float4 mk = *(const float4*)(tmk + c);
    float4 mv = *(const float4*)(tmv + c);
    float4 mr = *(const float4*)(tmr + c);
    ushort4 ok, ov, orr;
    ok.x = f2bf(xv4.x * mk.x + xp.x * (1.f - mk.x));
    ok.y = f2bf(xv4.y * mk.y + xp.y * (1.f - mk.y));
    ok.z = f2bf(xv4.z * mk.z + xp.z * (1.f - mk.z));
    ok.w = f2bf(xv4.w * mk.w + xp.w * (1.f - mk.w));
    ov.x = f2bf(xv4.x * mv.x + xp.x * (1.f - mv.x));
    ov.y = f2bf(xv4.y * mv.y + xp.y * (1.f - mv.y));
    ov.z = f2bf(xv4.z * mv.z + xp.z * (1.f - mv.z));
    ov.w = f2bf(xv4.w * mv.w + xp.w * (1.f - mv.w));
    orr.x = f2bf(xv4.x * mr.x + xp.x * (1.f - mr.x));
    orr.y = f2bf(xv4.y * mr.y + xp.y * (1.f - mr.y));
    orr.z = f2bf(xv4.z * mr.z + xp.z * (1.f - mr.z));
    orr.w = f2bf(xv4.w * mr.w + xp.w * (1.f - mr.w));
    *(ushort4*)(xk + e) = ok;
    *(ushort4*)(xv + e) = ov;
    *(ushort4*)(xr + e) = orr;
  }
}

// single-output mix (fallback path when ws is small)
__global__ __launch_bounds__(256) void mix_cast_kernel(const float* __restrict__ x,
                                const float* __restrict__ tmix,
                                unsigned short* __restrict__ out) {
  const size_t total4 = (size_t)BB * TT * CC / 4;
  for (size_t i = (size_t)blockIdx.x * blockDim.x + threadIdx.x; i < total4;
       i += (size_t)gridDim.x * blockDim.x) {
    size_t e = i * 4;
    int c = (int)(e & (CC - 1));
    int t = (int)((e / CC) & (TT - 1));
    float4 xv = ((const float4*)x)[i];
    float4 xp = make_float4(0.f, 0.f, 0.f, 0.f);
    if (t > 0) xp = ((const float4*)x)[i - CC / 4];
    float4 tm = *(const float4*)(tmix + c);
    ushort4 o;
    o.x = f2bf(xv.x * tm.x + xp.x * (1.f - tm.x));
    o.y = f2bf(xv.y * tm.y + xp.y * (1.f - tm.y));
    o.z = f2bf(xv.z * tm.z + xp.z * (1.f - tm.z));
    o.w = f2bf(xv.w * tm.w + xp.w * (1.f - tm.w));
    *(ushort4*)(out + e) = o;
  }
}

// all 4 weight casts in one launch
__global__ __launch_bounds__(256) void cast_w4_kernel(
    const float* __restrict__ w0, const float* __restrict__ w1,
    const float* __restrict__ w2, const float* __restrict__ w3,
    unsigned short* __restrict__ o0, unsigned short* __restrict__ o1,
    unsigned short* __restrict__ o2, unsigned short* __restrict__ o3) {
  const int n4 = CC * CC / 4;   // per weight
  for (int i = blockIdx.x * blockDim.x + threadIdx.x; i < 4 * n4;
       i += gridDim.x * blockDim.x) {
    int sel = i / n4;
    int j = i - sel * n4;
    const float* w = sel == 0 ? w0 : sel == 1 ? w1 : sel == 2 ? w2 : w3;
    unsigned short* o = sel == 0 ? o0 : sel == 1 ? o1 : sel == 2 ? o2 : o3;
    float4 v = ((const float4*)w)[j];
    ushort4 u;
    u.x = f2bf(v.x); u.y = f2bf(v.y); u.z = f2bf(v.z); u.w = f2bf(v.w);
    ((ushort4*)o)[j] = u;
  }
}

// ---- 256x256 8-phase GEMM (T2+T3+T4+T5) ---------------------------------
// C[m,n] = sum_k A[m,k]*B[n,k]; A:[M,K] bf16, B:[N,K] bf16 row-major, K=1024.
// 512 threads = 8 waves (2M x 4N). Wave wr owns A-rows wr*16 + 32*i (i=0..7),
// wave wc owns B-rows wc*16 + 64*j (j=0..3) -> phase quadrant (mh,nh) reads
// exactly staging half mh of A / nh of B. LDS: [2 dbuf][2 half][128][64] per
// matrix, pre-swizzled-global (slot ^= row&7), linear LDS dest (rule #21).
// LDS is declared ONCE in each __global__ kernel and passed in (a template
// body would otherwise duplicate a static __shared__ per instantiation).
// Counted vmcnt (per-wave) + s_barrier = cross-wave landing guarantee:
// P0 waits vmcnt(8) (retires A-h1(t)/B-h1(t) for P1/P2), P3 waits vmcnt(10)
// (retires A-h0(t+1)/B-h0(t+1) for next P0). Never drained to 0 in the loop.
#define NT8 (CC / 64)   // 16 K-tiles

template <typename EPI>
__device__ __forceinline__ void gemm8_body(unsigned short* lds8,
                                           const unsigned short* __restrict__ A,
                                           const unsigned short* __restrict__ Bm,
                                           int tm, int tn, EPI epi) {
  const int tid = threadIdx.x;
  const int lane = tid & 63;
  const int wid = tid >> 6;
  const int wr = wid >> 2;   // 0..1
  const int wc = wid & 3;    // 0..3
  const int fr = lane & 15;
  const int fk = lane >> 4;  // 0..3

  // staging: 512 threads x 16B = 64 rows x 64 cols per GLOAD16 round
  const int srow = tid >> 3;                          // 0..63
  const int gcol = (((tid & 7) ^ (srow & 7)) << 3);   // pre-swizzled global col
  const unsigned short* Ag = A + (size_t)(tm * 256 + srow) * CC + gcol;
  const unsigned short* Bg = Bm + (size_t)(tn * 256 + srow) * CC + gcol;
  const int ldst = tid << 3;                          // linear LDS dest (elems)

  const int rowA = wr * 16 + fr;
  const int rowB = wc * 16 + fr;
  const int sx0 = ((fk ^ (fr & 7)) << 3);             // read-side un-swizzle, kk=0
  const int sx1 = (((4 + fk) ^ (fr & 7)) << 3);       // kk=1

  bf16x8_t aF[4][2];      // current mh half: [i][kk]
  bf16x8_t bF[2][2][2];   // both nh halves:  [nh][j][kk]
  f32x4_t acc[8][4] = {};

#define STG_A(T, H)                                                            \
  {                                                                            \
    const unsigned short* g_ = Ag + (size_t)((H) * 128) * CC + (T) * 64;       \
    unsigned short* l_ = &lds8[(((T) & 1) << 14) + (H) * 8192 + ldst];         \
    GLOAD16(g_, l_);                                                           \
    GLOAD16(g_ + (size_t)64 * CC, l_ + 4096);                                  \
  }
#define STG_B(T, H)                                                            \
  {                                                                            \
    const unsigned short* g_ = Bg + (size_t)((H) * 128) * CC + (T) * 64;       \
    unsigned short* l_ = &lds8[32768 + (((T) & 1) << 14) + (H) * 8192 + ldst]; \
    GLOAD16(g_, l_);                                                           \
    GLOAD16(g_ + (size_t)64 * CC, l_ + 4096);                                  \
  }
#define LOADA(MH)                                                              \
  _Pragma("unroll") for (int i_ = 0; i_ < 4; ++i_) {                           \
    aF[i_][0] = *(const bf16x8_t*)&lds8[ab + ((MH) * 4 + i_) * 2048 + sx0];    \
    aF[i_][1] = *(const bf16x8_t*)&lds8[ab + ((MH) * 4 + i_) * 2048 + sx1];    \
  }
#define LOADB(NH)                                                              \
  _Pragma("unroll") for (int j_ = 0; j_ < 2; ++j_) {                           \
    bF[NH][j_][0] = *(const bf16x8_t*)&lds8[bb + ((NH) * 2 + j_) * 4096 + sx0];\
    bF[NH][j_][1] = *(const bf16x8_t*)&lds8[bb + ((NH) * 2 + j_) * 4096 + sx1];\
  }
#define MFMAQ(MH, NH)                                                          \
  _Pragma("unroll") for (int i_ = 0; i_ < 4; ++i_)                             \
  _Pragma("unroll") for (int j_ = 0; j_ < 2; ++j_) {                           \
    acc[(MH) * 4 + i_][(NH) * 2 + j_] = __builtin_amdgcn_mfma_f32_16x16x32_bf16( \
        aF[i_][0], bF[NH][j_][0], acc[(MH) * 4 + i_][(NH) * 2 + j_], 0, 0, 0); \
    acc[(MH) * 4 + i_][(NH) * 2 + j_] = __builtin_amdgcn_mfma_f32_16x16x32_bf16( \
        aF[i_][1], bF[NH][j_][1], acc[(MH) * 4 + i_][(NH) * 2 + j_], 0, 0, 0); \
  }

  // prologue: tile0 full + tile1 {A-h0, B-h0, A-h1}; wait lands A00/B00
  STG_A(0, 0) STG_B(0, 0) STG_A(0, 1) STG_B(0, 1)
  STG_A(1, 0) STG_B(1, 0) STG_A(1, 1)
  asm volatile("s_waitcnt vmcnt(10)" ::: "memory");
  __builtin_amdgcn_s_barrier();

  for (int t = 0; t < NT8; ++t) {
    const int ab = ((t & 1) << 14) + rowA * 64;
    const int bb = 32768 + ((t & 1) << 14) + rowB * 64;
    // ---- P0 (mh0, nh0): read A-h0+B-h0; stage B-h1(t+1); vmcnt(8)
    LOADA(0) LOADB(0)
    if (t + 1 < NT8) { STG_B(t + 1, 1) }
    asm volatile("s_waitcnt vmcnt(8)" ::: "memory");
    __builtin_amdgcn_s_barrier();
    __builtin_amdgcn_s_setprio(1);
    MFMAQ(0, 0)
    __builtin_amdgcn_s_setprio(0);
    __builtin_amdgcn_s_barrier();
    // ---- P1 (mh0, nh1): read B-h1 (A reg-held); stage A-h0(t+2)
    LOADB(1)
    if (t + 2 < NT8) { STG_A(t + 2, 0) }
    __builtin_amdgcn_s_barrier();
    __builtin_amdgcn_s_setprio(1);
    MFMAQ(0, 1)
    __builtin_amdgcn_s_setprio(0);
    __builtin_amdgcn_s_barrier();
    // ---- P2 (mh1, nh0): read A-h1 (B-h0 reg-held); stage B-h0(t+2)
    LOADA(1)
    if (t + 2 < NT8) { STG_B(t + 2, 0) }
    __builtin_amdgcn_s_barrier();
    __builtin_amdgcn_s_setprio(1);
    MFMAQ(1, 0)
    __builtin_amdgcn_s_setprio(0);
    __builtin_amdgcn_s_barrier();
    // ---- P3 (mh1, nh1): all reg-held; stage A-h1(t+2); vmcnt(10)
    if (t + 2 < NT8) { STG_A(t + 2, 1) }
    asm volatile("s_waitcnt vmcnt(10)" ::: "memory");
    __builtin_amdgcn_s_barrier();
    __builtin_amdgcn_s_setprio(1);
    MFMAQ(1, 1)
    __builtin_amdgcn_s_setprio(0);
    __builtin_amdgcn_s_barrier();
  }

  // epilogue: C/D layout col=lane&15, row=fk*4+rg; frag (im,jn) at
  // rows wr*16+32*im, cols wc*16+64*jn (interleaved wave mapping)
#pragma unroll
  for (int im = 0; im < 8; ++im)
#pragma unroll
    for (int jn = 0; jn < 4; ++jn)
#pragma unroll
      for (int rg = 0; rg < 4; ++rg)
        epi((size_t)(tm * 256 + wr * 16 + im * 32 + (fk << 2) + rg) * CC +
                (size_t)(tn * 256 + wc * 16 + jn * 64 + fr),
            acc[im][jn][rg]);
#undef STG_A
#undef STG_B
#undef LOADA
#undef LOADB
#undef MFMAQ
}

// merged k/v/r projection: 768 blocks, XCD-swizzled (768%8==0, bijective)
__global__ __launch_bounds__(512, 2) void gemm8_kvr(
    const unsigned short* __restrict__ xk, const unsigned short* __restrict__ xv,
    const unsigned short* __restrict__ xr, const unsigned short* __restrict__ Wk,
    const unsigned short* __restrict__ Wv, const unsigned short* __restrict__ Wr,
    float* __restrict__ kout, unsigned short* __restrict__ vout,
    unsigned short* __restrict__ rout) {
  __shared__ unsigned short lds8[65536];   // 128 KB, shared by all body calls
  int orig = blockIdx.x;
  int wg = (orig & 7) * 96 + (orig >> 3);
  int which = wg >> 8;        // /256 tiles per matrix
  int rr = wg & 255;
  int tm = rr >> 2;           // tn-fast within XCD chunk
  int tn = rr & 3;
  if (which == 0) {
    gemm8_body(lds8, xk, Wk, tm, tn,
               [&](size_t off, float val) { kout[off] = val; });
  } else {
    const unsigned short* A = which == 1 ? xv : xr;
    const unsigned short* Bm = which == 1 ? Wv : Wr;
    unsigned short* o = which == 1 ? vout : rout;
    gemm8_body(lds8, A, Bm, tm, tn,
               [&](size_t off, float val) { o[off] = f2bf(val); });
  }
}

// single GEMM (256 blocks, XCD-swizzled), fp32 or bf16 out
template <int OUT_BF16>
__global__ __launch_bounds__(512, 2) void gemm8_one(const unsigned short* __restrict__ A,
                         const unsigned short* __restrict__ Bm,
                         void* __restrict__ Cm) {
  __shared__ unsigned short lds8[65536];   // 128 KB
  int orig = blockIdx.x;
  int wg = (orig & 7) * 32 + (orig >> 3);
  int tm = wg >> 2;
  int tn = wg & 3;
  if (OUT_BF16)
    gemm8_body(lds8, A, Bm, tm, tn,
               [&](size_t off, float val) { ((unsigned short*)Cm)[off] = f2bf(val); });
  else
    gemm8_body(lds8, A, Bm, tm, tn,
               [&](size_t off, float val) { ((float*)Cm)[off] = val; });
}

// ---- Chunk-parallel WKV scan --------------------------------------------
__global__ __launch_bounds__(256) void wkv_phase1(const float* __restrict__ k,
                           const unsigned short* __restrict__ v,
                           const float* __restrict__ wdec,
                           float* __restrict__ Sa, float* __restrict__ Sb,
                           float* __restrict__ Sp) {
  int idx = blockIdx.x * blockDim.x + threadIdx.x;
  int c = idx & (CC - 1);
  int bj = idx >> 10;
  int j = bj % WKV_NCH;
  int b = bj / WKV_NCH;
  float w = -__expf(wdec[c]);
  size_t base = (size_t)b * TT * CC + (size_t)j * WKV_L * CC + c;
  float aa = 0.f, bb = 0.f, pp = -1e38f;
  for (int t = 0; t < WKV_L; ++t) {
    size_t off = base + (size_t)t * CC;
    float kt = k[off];
    float vt = bf2f(v[off]);
    float ww2 = pp + w;
    float q2 = fmaxf(ww2, kt);
    float f1 = __expf(ww2 - q2);
    float f2 = __expf(kt - q2);
    aa = fmaf(f1, aa, f2 * vt);
    bb = fmaf(f1, bb, f2);
    pp = q2;
  }
  Sa[idx] = aa; Sb[idx] = bb; Sp[idx] = pp;
}

__global__ __launch_bounds__(256) void wkv_phase2(const float* __restrict__ wdec,
                           const float* __restrict__ Sa, const float* __restrict__ Sb,
                           const float* __restrict__ Sp,
                           float* __restrict__ Ia, float* __restrict__ Ib,
                           float* __restrict__ Ip) {
  int idx = blockIdx.x * blockDim.x + threadIdx.x;
  if (idx >= BB * CC) return;
  int c = idx & (CC - 1);
  int b = idx >> 10;
  float wL = -__expf(wdec[c]) * (float)WKV_L;
  float aa = 0.f, bb = 0.f, pp = -1e38f;
  for (int j = 0; j < WKV_NCH; ++j) {
    size_t s = (size_t)(b * WKV_NCH + j) * CC + c;
    Ia[s] = aa; Ib[s] = bb; Ip[s] = pp;
    float pd = pp + wL;
    float ps = Sp[s];
    float q = fmaxf(pd, ps);
    float e1 = __expf(pd - q);
    float e2 = __expf(ps - q);
    aa = fmaf(e1, aa, e2 * Sa[s]);
    bb = fmaf(e1, bb, e2 * Sb[s]);
    pp = q;
  }
}

__global__ __launch_bounds__(256) void wkv_phase3(const float* __restrict__ k,
                           const unsigned short* __restrict__ v,
                           const unsigned short* __restrict__ r,
                           const float* __restrict__ wdec,
                           const float* __restrict__ u,
                           const float* __restrict__ Ia, const float* __restrict__ Ib,
                           const float* __restrict__ Ip,
                           unsigned short* __restrict__ out) {
  int idx = blockIdx.x * blockDim.x + threadIdx.x;
  int c = idx & (CC - 1);
  int bj = idx >> 10;
  int j = bj % WKV_NCH;
  int b = bj / WKV_NCH;
  float w = -__expf(wdec[c]);
  float uu = u[c];
  float aa = Ia[idx], bb = Ib[idx], pp = Ip[idx];
  size_t base = (size_t)b * TT * CC + (size_t)j * WKV_L * CC + c;
  for (int t = 0; t < WKV_L; ++t) {
    size_t off = base + (size_t)t * CC;
    float kt = k[off];
    float vt = bf2f(v[off]);
    float ww = uu + kt;
    float q = fmaxf(pp, ww);
    float e1 = __expf(pp - q);
    float e2 = __expf(ww - q);
    float y = fmaf(e1, aa, e2 * vt) / fmaf(e1, bb, e2);
    float ww2 = pp + w;
    float q2 = fmaxf(ww2, kt);
    float f1 = __expf(ww2 - q2);
    float f2 = __expf(kt - q2);
    aa = fmaf(f1, aa, f2 * vt);
    bb = fmaf(f1, bb, f2);
    pp = q2;
    float rt = bf2f(r[off]);
    float sr = 1.f / (1.f + __expf(-rt));
    out[off] = f2bf(sr * y);
  }
}

extern "C" void kernel_launch(void* const* d_in, const int* in_sizes, int n_in,
                              void* d_out, int out_size, void* d_ws, size_t ws_size,
                              hipStream_t stream) {
  const float* x    = (const float*)d_in[0];
  const float* tdec = (const float*)d_in[1];
  const float* tfir = (const float*)d_in[2];
  const float* tmk  = (const float*)d_in[3];
  const float* tmv  = (const float*)d_in[4];
  const float* tmr  = (const float*)d_in[5];
  const float* Wk   = (const float*)d_in[6];
  const float* Wv   = (const float*)d_in[7];
  const float* Wr   = (const float*)d_in[8];
  const float* Wo   = (const float*)d_in[9];

  const size_t M = (size_t)BB * TT;     // 16384
  const size_t mixbytes = M * CC * 2;   // 33.5 MB
  const size_t wbytes = (size_t)CC * CC * 2;
  const size_t nstate = (size_t)BB * WKV_NCH * CC;

  const size_t need_big = 3 * mixbytes + 4 * wbytes + (M * CC * 4) + 2 * mixbytes +
                          mixbytes + 6 * nstate * 4;
  const bool big = ws_size >= need_big;

  char* ws = (char*)d_ws;
  unsigned short* xkb = (unsigned short*)ws; ws += mixbytes;
  unsigned short* xvb = xkb, *xrb = xkb;
  if (big) {
    xvb = (unsigned short*)ws; ws += mixbytes;
    xrb = (unsigned short*)ws; ws += mixbytes;
  }
  unsigned short* Wkb = (unsigned short*)ws; ws += wbytes;
  unsigned short* Wvb = (unsigned short*)ws; ws += wbytes;
  unsigned short* Wrb = (unsigned short*)ws; ws += wbytes;
  unsigned short* Wob = (unsigned short*)ws; ws += wbytes;
  float* kbuf = (float*)ws;                   ws += M * CC * 4;
  unsigned short* vbuf = (unsigned short*)ws; ws += mixbytes;
  unsigned short* rbuf = (unsigned short*)ws; ws += mixbytes;
  float* Sa = (float*)ws; ws += nstate * 4;
  float* Sb = (float*)ws; ws += nstate * 4;
  float* Sp = (float*)ws; ws += nstate * 4;
  float* Ia = (float*)ws; ws += nstate * 4;
  float* Ib = (float*)ws; ws += nstate * 4;
  float* Ip = (float*)ws; ws += nstate * 4;

  dim3 blk(256);
  dim3 blk8(512);
  const int wkv_grid = (int)(nstate / 256);               // 1024

  cast_w4_kernel<<<1024, blk, 0, stream>>>(Wk, Wv, Wr, Wo, Wkb, Wvb, Wrb, Wob);

  if (big) {
    mix3_cast_kernel<<<2048, blk, 0, stream>>>(x, tmk, tmv, tmr, xkb, xvb, xrb);
    gemm8_kvr<<<768, blk8, 0, stream>>>(xkb, xvb, xrb, Wkb, Wvb, Wrb,
                                        kbuf, vbuf, rbuf);
  } else {
    mix_cast_kernel<<<2048, blk, 0, stream>>>(x, tmk, xkb);
    gemm8_one<0><<<256, blk8, 0, stream>>>(xkb, Wkb, kbuf);
    mix_cast_kernel<<<2048, blk, 0, stream>>>(x, tmv, xkb);
    gemm8_one<1><<<256, blk8, 0, stream>>>(xkb, Wvb, vbuf);
    mix_cast_kernel<<<2048, blk, 0, stream>>>(x, tmr, xkb);
    gemm8_one<1><<<256, blk8, 0, stream>>>(xkb, Wrb, rbuf);
  }

  wkv_phase1<<<wkv_grid, blk, 0, stream>>>(kbuf, vbuf, tdec, Sa, Sb, Sp);
  wkv_phase2<<<(BB * CC + 255) / 256, blk, 0, stream>>>(tdec, Sa, Sb, Sp, Ia, Ib, Ip);
  wkv_phase3<<<wkv_grid, blk, 0, stream>>>(kbuf, vbuf, rbuf, tdec, tfir, Ia, Ib, Ip, xkb);

  gemm8_one<0><<<256, blk8, 0, stream>>>(xkb, Wob, d_out);
}

// Round 7
// 273.900 us; speedup vs baseline: 4.5927x; 1.0651x over previous
//
#include <hip/hip_runtime.h>

#define BB 8
#define TT 2048
#define CC 1024
#define WKV_L 64
#define WKV_NCH (TT / WKV_L)   // 32 chunks

typedef __bf16 bf16x8_t __attribute__((ext_vector_type(8)));
typedef float f32x4_t __attribute__((ext_vector_type(4)));

__device__ __forceinline__ unsigned short f2bf(float f) {
  unsigned u = __float_as_uint(f);
  u += 0x7fffu + ((u >> 16) & 1u);   // round-to-nearest-even
  return (unsigned short)(u >> 16);
}
__device__ __forceinline__ float bf2f(unsigned short s) {
  return __uint_as_float(((unsigned)s) << 16);
}

#define GLOAD16(gp, lp)                                                        \
  __builtin_amdgcn_global_load_lds(                                            \
      (const __attribute__((address_space(1))) void*)(gp),                     \
      (__attribute__((address_space(3))) void*)(lp), 16, 0, 0)

// ---- time-shift mix: xk, xv in one pass over x --------------------------
__global__ __launch_bounds__(256) void mix2_cast_kernel(
    const float* __restrict__ x, const float* __restrict__ tmk,
    const float* __restrict__ tmv,
    unsigned short* __restrict__ xk, unsigned short* __restrict__ xv) {
  const size_t total4 = (size_t)BB * TT * CC / 4;
  for (size_t i = (size_t)blockIdx.x * blockDim.x + threadIdx.x; i < total4;
       i += (size_t)gridDim.x * blockDim.x) {
    size_t e = i * 4;
    int c = (int)(e & (CC - 1));
    int t = (int)((e / CC) & (TT - 1));
    float4 xv4 = ((const float4*)x)[i];
    float4 xp = make_float4(0.f, 0.f, 0.f, 0.f);
    if (t > 0) xp = ((const float4*)x)[i - CC / 4];
    float4 mk = *(const float4*)(tmk + c);
    float4 mv = *(const float4*)(tmv + c);
    ushort4 ok, ov;
    ok.x = f2bf(xv4.x * mk.x + xp.x * (1.f - mk.x));
    ok.y = f2bf(xv4.y * mk.y + xp.y * (1.f - mk.y));
    ok.z = f2bf(xv4.z * mk.z + xp.z * (1.f - mk.z));
    ok.w = f2bf(xv4.w * mk.w + xp.w * (1.f - mk.w));
    ov.x = f2bf(xv4.x * mv.x + xp.x * (1.f - mv.x));
    ov.y = f2bf(xv4.y * mv.y + xp.y * (1.f - mv.y));
    ov.z = f2bf(xv4.z * mv.z + xp.z * (1.f - mv.z));
    ov.w = f2bf(xv4.w * mv.w + xp.w * (1.f - mv.w));
    *(ushort4*)(xk + e) = ok;
    *(ushort4*)(xv + e) = ov;
  }
}

// single-output mix (used for xr after xkb is dead)
__global__ __launch_bounds__(256) void mix_cast_kernel(const float* __restrict__ x,
                                const float* __restrict__ tmix,
                                unsigned short* __restrict__ out) {
  const size_t total4 = (size_t)BB * TT * CC / 4;
  for (size_t i = (size_t)blockIdx.x * blockDim.x + threadIdx.x; i < total4;
       i += (size_t)gridDim.x * blockDim.x) {
    size_t e = i * 4;
    int c = (int)(e & (CC - 1));
    int t = (int)((e / CC) & (TT - 1));
    float4 xv = ((const float4*)x)[i];
    float4 xp = make_float4(0.f, 0.f, 0.f, 0.f);
    if (t > 0) xp = ((const float4*)x)[i - CC / 4];
    float4 tm = *(const float4*)(tmix + c);
    ushort4 o;
    o.x = f2bf(xv.x * tm.x + xp.x * (1.f - tm.x));
    o.y = f2bf(xv.y * tm.y + xp.y * (1.f - tm.y));
    o.z = f2bf(xv.z * tm.z + xp.z * (1.f - tm.z));
    o.w = f2bf(xv.w * tm.w + xp.w * (1.f - tm.w));
    *(ushort4*)(out + e) = o;
  }
}

// all 4 weight casts in one launch
__global__ __launch_bounds__(256) void cast_w4_kernel(
    const float* __restrict__ w0, const float* __restrict__ w1,
    const float* __restrict__ w2, const float* __restrict__ w3,
    unsigned short* __restrict__ o0, unsigned short* __restrict__ o1,
    unsigned short* __restrict__ o2, unsigned short* __restrict__ o3) {
  const int n4 = CC * CC / 4;   // per weight
  for (int i = blockIdx.x * blockDim.x + threadIdx.x; i < 4 * n4;
       i += gridDim.x * blockDim.x) {
    int sel = i / n4;
    int j = i - sel * n4;
    const float* w = sel == 0 ? w0 : sel == 1 ? w1 : sel == 2 ? w2 : w3;
    unsigned short* o = sel == 0 ? o0 : sel == 1 ? o1 : sel == 2 ? o2 : o3;
    float4 v = ((const float4*)w)[j];
    ushort4 u;
    u.x = f2bf(v.x); u.y = f2bf(v.y); u.z = f2bf(v.z); u.w = f2bf(v.w);
    ((ushort4*)o)[j] = u;
  }
}

// ---- 256x256 8-phase GEMM (T2+T3+T4+T5), K-loop fully unrolled ----------
// C[m,n] = sum_k A[m,k]*B[n,k]; A:[M,K] bf16, B:[N,K] bf16 row-major, K=1024.
// 512 threads = 8 waves (2M x 4N). Wave wr owns A-rows wr*16 + 32*i (i=0..7),
// wave wc owns B-rows wc*16 + 64*j (j=0..3) -> phase quadrant (mh,nh) reads
// exactly staging half mh of A / nh of B. LDS: [2 dbuf][2 half][128][64] per
// matrix, pre-swizzled-global (slot ^= row&7), linear LDS dest (rule #21).
// Counted vmcnt (per-wave) + s_barrier = cross-wave landing guarantee:
// P0 waits vmcnt(8), P3 waits vmcnt(10). Never drained to 0 in the loop.
// NT8=16 known at compile time -> #pragma unroll makes every LDS offset an
// immediate and removes the guard branches (R6 ran this rolled at ~6450
// cyc/K-tile vs m201's ~3000; addressing/front-end overhead is the target).
#define NT8 (CC / 64)   // 16 K-tiles

template <typename EPI>
__device__ __forceinline__ void gemm8_body(unsigned short* lds8,
                                           const unsigned short* __restrict__ A,
                                           const unsigned short* __restrict__ Bm,
                                           int tm, int tn, EPI epi) {
  const int tid = threadIdx.x;
  const int lane = tid & 63;
  const int wid = tid >> 6;
  const int wr = wid >> 2;   // 0..1
  const int wc = wid & 3;    // 0..3
  const int fr = lane & 15;
  const int fk = lane >> 4;  // 0..3

  // staging: 512 threads x 16B = 64 rows x 64 cols per GLOAD16 round
  const int srow = tid >> 3;                          // 0..63
  const int gcol = (((tid & 7) ^ (srow & 7)) << 3);   // pre-swizzled global col
  const unsigned short* Ag = A + (size_t)(tm * 256 + srow) * CC + gcol;
  const unsigned short* Bg = Bm + (size_t)(tn * 256 + srow) * CC + gcol;
  const int ldst = tid << 3;                          // linear LDS dest (elems)

  const int rowA = wr * 16 + fr;
  const int rowB = wc * 16 + fr;
  const int sx0 = ((fk ^ (fr & 7)) << 3);             // read-side un-swizzle, kk=0
  const int sx1 = (((4 + fk) ^ (fr & 7)) << 3);       // kk=1

  bf16x8_t aF[4][2];      // current mh half: [i][kk]
  bf16x8_t bF[2][2][2];   // both nh halves:  [nh][j][kk]
  f32x4_t acc[8][4] = {};

#define STG_A(T, H)                                                            \
  {                                                                            \
    const unsigned short* g_ = Ag + (size_t)((H) * 128) * CC + (T) * 64;       \
    unsigned short* l_ = &lds8[(((T) & 1) << 14) + (H) * 8192 + ldst];         \
    GLOAD16(g_, l_);                                                           \
    GLOAD16(g_ + (size_t)64 * CC, l_ + 4096);                                  \
  }
#define STG_B(T, H)                                                            \
  {                                                                            \
    const unsigned short* g_ = Bg + (size_t)((H) * 128) * CC + (T) * 64;       \
    unsigned short* l_ = &lds8[32768 + (((T) & 1) << 14) + (H) * 8192 + ldst]; \
    GLOAD16(g_, l_);                                                           \
    GLOAD16(g_ + (size_t)64 * CC, l_ + 4096);                                  \
  }
#define LOADA(MH)                                                              \
  _Pragma("unroll") for (int i_ = 0; i_ < 4; ++i_) {                           \
    aF[i_][0] = *(const bf16x8_t*)&lds8[ab + ((MH) * 4 + i_) * 2048 + sx0];    \
    aF[i_][1] = *(const bf16x8_t*)&lds8[ab + ((MH) * 4 + i_) * 2048 + sx1];    \
  }
#define LOADB(NH)                                                              \
  _Pragma("unroll") for (int j_ = 0; j_ < 2; ++j_) {                           \
    bF[NH][j_][0] = *(const bf16x8_t*)&lds8[bb + ((NH) * 2 + j_) * 4096 + sx0];\
    bF[NH][j_][1] = *(const bf16x8_t*)&lds8[bb + ((NH) * 2 + j_) * 4096 + sx1];\
  }
#define MFMAQ(MH, NH)                                                          \
  _Pragma("unroll") for (int i_ = 0; i_ < 4; ++i_)                             \
  _Pragma("unroll") for (int j_ = 0; j_ < 2; ++j_) {                           \
    acc[(MH) * 4 + i_][(NH) * 2 + j_] = __builtin_amdgcn_mfma_f32_16x16x32_bf16( \
        aF[i_][0], bF[NH][j_][0], acc[(MH) * 4 + i_][(NH) * 2 + j_], 0, 0, 0); \
    acc[(MH) * 4 + i_][(NH) * 2 + j_] = __builtin_amdgcn_mfma_f32_16x16x32_bf16( \
        aF[i_][1], bF[NH][j_][1], acc[(MH) * 4 + i_][(NH) * 2 + j_], 0, 0, 0); \
  }

  // prologue: tile0 full + tile1 {A-h0, B-h0, A-h1}; wait lands A00/B00
  STG_A(0, 0) STG_B(0, 0) STG_A(0, 1) STG_B(0, 1)
  STG_A(1, 0) STG_B(1, 0) STG_A(1, 1)
  asm volatile("s_waitcnt vmcnt(10)" ::: "memory");
  __builtin_amdgcn_s_barrier();

#pragma unroll
  for (int t = 0; t < NT8; ++t) {
    const int ab = ((t & 1) << 14) + rowA * 64;
    const int bb = 32768 + ((t & 1) << 14) + rowB * 64;
    // ---- P0 (mh0, nh0): read A-h0+B-h0; stage B-h1(t+1); vmcnt(8)
    LOADA(0) LOADB(0)
    if (t + 1 < NT8) { STG_B(t + 1, 1) }
    asm volatile("s_waitcnt vmcnt(8)" ::: "memory");
    __builtin_amdgcn_s_barrier();
    __builtin_amdgcn_s_setprio(1);
    MFMAQ(0, 0)
    __builtin_amdgcn_s_setprio(0);
    __builtin_amdgcn_s_barrier();
    // ---- P1 (mh0, nh1): read B-h1 (A reg-held); stage A-h0(t+2)
    LOADB(1)
    if (t + 2 < NT8) { STG_A(t + 2, 0) }
    __builtin_amdgcn_s_barrier();
    __builtin_amdgcn_s_setprio(1);
    MFMAQ(0, 1)
    __builtin_amdgcn_s_setprio(0);
    __builtin_amdgcn_s_barrier();
    // ---- P2 (mh1, nh0): read A-h1 (B-h0 reg-held); stage B-h0(t+2)
    LOADA(1)
    if (t + 2 < NT8) { STG_B(t + 2, 0) }
    __builtin_amdgcn_s_barrier();
    __builtin_amdgcn_s_setprio(1);
    MFMAQ(1, 0)
    __builtin_amdgcn_s_setprio(0);
    __builtin_amdgcn_s_barrier();
    // ---- P3 (mh1, nh1): all reg-held; stage A-h1(t+2); vmcnt(10)
    if (t + 2 < NT8) { STG_A(t + 2, 1) }
    asm volatile("s_waitcnt vmcnt(10)" ::: "memory");
    __builtin_amdgcn_s_barrier();
    __builtin_amdgcn_s_setprio(1);
    MFMAQ(1, 1)
    __builtin_amdgcn_s_setprio(0);
    __builtin_amdgcn_s_barrier();
  }

  // epilogue: C/D layout col=lane&15, row=fk*4+rg; frag (im,jn) at
  // rows wr*16+32*im, cols wc*16+64*jn (interleaved wave mapping)
#pragma unroll
  for (int im = 0; im < 8; ++im)
#pragma unroll
    for (int jn = 0; jn < 4; ++jn)
#pragma unroll
      for (int rg = 0; rg < 4; ++rg)
        epi((size_t)(tm * 256 + wr * 16 + im * 32 + (fk << 2) + rg) * CC +
                (size_t)(tn * 256 + wc * 16 + jn * 64 + fr),
            acc[im][jn][rg]);
#undef STG_A
#undef STG_B
#undef LOADA
#undef LOADB
#undef MFMAQ
}

// single GEMM (256 blocks, XCD-swizzled), fp32 or bf16 out
template <int OUT_BF16>
__global__ __launch_bounds__(512, 2) void gemm8_one(const unsigned short* __restrict__ A,
                         const unsigned short* __restrict__ Bm,
                         void* __restrict__ Cm) {
  __shared__ unsigned short lds8[65536];   // 128 KB
  int orig = blockIdx.x;
  int wg = (orig & 7) * 32 + (orig >> 3);
  int tm = wg >> 2;
  int tn = wg & 3;
  if (OUT_BF16)
    gemm8_body(lds8, A, Bm, tm, tn,
               [&](size_t off, float val) { ((unsigned short*)Cm)[off] = f2bf(val); });
  else
    gemm8_body(lds8, A, Bm, tm, tn,
               [&](size_t off, float val) { ((float*)Cm)[off] = val; });
}

// ---- Chunk-parallel WKV scan --------------------------------------------
__global__ __launch_bounds__(256) void wkv_phase1(const float* __restrict__ k,
                           const unsigned short* __restrict__ v,
                           const float* __restrict__ wdec,
                           float* __restrict__ Sa, float* __restrict__ Sb,
                           float* __restrict__ Sp) {
  int idx = blockIdx.x * blockDim.x + threadIdx.x;
  int c = idx & (CC - 1);
  int bj = idx >> 10;
  int j = bj % WKV_NCH;
  int b = bj / WKV_NCH;
  float w = -__expf(wdec[c]);
  size_t base = (size_t)b * TT * CC + (size_t)j * WKV_L * CC + c;
  float aa = 0.f, bb = 0.f, pp = -1e38f;
  for (int t = 0; t < WKV_L; ++t) {
    size_t off = base + (size_t)t * CC;
    float kt = k[off];
    float vt = bf2f(v[off]);
    float ww2 = pp + w;
    float q2 = fmaxf(ww2, kt);
    float f1 = __expf(ww2 - q2);
    float f2 = __expf(kt - q2);
    aa = fmaf(f1, aa, f2 * vt);
    bb = fmaf(f1, bb, f2);
    pp = q2;
  }
  Sa[idx] = aa; Sb[idx] = bb; Sp[idx] = pp;
}

__global__ __launch_bounds__(256) void wkv_phase2(const float* __restrict__ wdec,
                           const float* __restrict__ Sa, const float* __restrict__ Sb,
                           const float* __restrict__ Sp,
                           float* __restrict__ Ia, float* __restrict__ Ib,
                           float* __restrict__ Ip) {
  int idx = blockIdx.x * blockDim.x + threadIdx.x;
  if (idx >= BB * CC) return;
  int c = idx & (CC - 1);
  int b = idx >> 10;
  float wL = -__expf(wdec[c]) * (float)WKV_L;
  float aa = 0.f, bb = 0.f, pp = -1e38f;
  for (int j = 0; j < WKV_NCH; ++j) {
    size_t s = (size_t)(b * WKV_NCH + j) * CC + c;
    Ia[s] = aa; Ib[s] = bb; Ip[s] = pp;
    float pd = pp + wL;
    float ps = Sp[s];
    float q = fmaxf(pd, ps);
    float e1 = __expf(pd - q);
    float e2 = __expf(ps - q);
    aa = fmaf(e1, aa, e2 * Sa[s]);
    bb = fmaf(e1, bb, e2 * Sb[s]);
    pp = q;
  }
}

// phase3 with IN-PLACE gate: out == r is allowed (each offset is read then
// written by the same owning thread) -> no __restrict__ on r/out.
__global__ __launch_bounds__(256) void wkv_phase3(const float* __restrict__ k,
                           const unsigned short* __restrict__ v,
                           const unsigned short* r,
                           const float* __restrict__ wdec,
                           const float* __restrict__ u,
                           const float* __restrict__ Ia, const float* __restrict__ Ib,
                           const float* __restrict__ Ip,
                           unsigned short* out) {
  int idx = blockIdx.x * blockDim.x + threadIdx.x;
  int c = idx & (CC - 1);
  int bj = idx >> 10;
  int j = bj % WKV_NCH;
  int b = bj / WKV_NCH;
  float w = -__expf(wdec[c]);
  float uu = u[c];
  float aa = Ia[idx], bb = Ib[idx], pp = Ip[idx];
  size_t base = (size_t)b * TT * CC + (size_t)j * WKV_L * CC + c;
  for (int t = 0; t < WKV_L; ++t) {
    size_t off = base + (size_t)t * CC;
    float kt = k[off];
    float vt = bf2f(v[off]);
    float ww = uu + kt;
    float q = fmaxf(pp, ww);
    float e1 = __expf(pp - q);
    float e2 = __expf(ww - q);
    float y = fmaf(e1, aa, e2 * vt) / fmaf(e1, bb, e2);
    float ww2 = pp + w;
    float q2 = fmaxf(ww2, kt);
    float f1 = __expf(ww2 - q2);
    float f2 = __expf(kt - q2);
    aa = fmaf(f1, aa, f2 * vt);
    bb = fmaf(f1, bb, f2);
    pp = q2;
    float rt = bf2f(r[off]);
    float sr = 1.f / (1.f + __expf(-rt));
    out[off] = f2bf(sr * y);
  }
}

extern "C" void kernel_launch(void* const* d_in, const int* in_sizes, int n_in,
                              void* d_out, int out_size, void* d_ws, size_t ws_size,
                              hipStream_t stream) {
  const float* x    = (const float*)d_in[0];
  const float* tdec = (const float*)d_in[1];
  const float* tfir = (const float*)d_in[2];
  const float* tmk  = (const float*)d_in[3];
  const float* tmv  = (const float*)d_in[4];
  const float* tmr  = (const float*)d_in[5];
  const float* Wk   = (const float*)d_in[6];
  const float* Wv   = (const float*)d_in[7];
  const float* Wr   = (const float*)d_in[8];
  const float* Wo   = (const float*)d_in[9];

  const size_t M = (size_t)BB * TT;     // 16384
  const size_t mixbytes = M * CC * 2;   // 33.5 MB
  const size_t wbytes = (size_t)CC * CC * 2;
  const size_t nstate = (size_t)BB * WKV_NCH * CC;

  // Overlay plan (182.4 MB total == R6 footprint, known to fit):
  //  R1: xkb   (mix2 -> k-gemm; then xr mix -> r-gemm)
  //  R2: xvb   (mix2 -> v-gemm; then rbuf = r-gemm out -> p3 in-place -> final gemm)
  char* ws = (char*)d_ws;
  unsigned short* xkb = (unsigned short*)ws;  ws += mixbytes;   // R1
  unsigned short* xvb = (unsigned short*)ws;  ws += mixbytes;   // R2
  unsigned short* rbuf = xvb;                                    // alias (see plan)
  unsigned short* Wkb = (unsigned short*)ws; ws += wbytes;
  unsigned short* Wvb = (unsigned short*)ws; ws += wbytes;
  unsigned short* Wrb = (unsigned short*)ws; ws += wbytes;
  unsigned short* Wob = (unsigned short*)ws; ws += wbytes;
  float* kbuf = (float*)ws;                   ws += M * CC * 4;
  unsigned short* vbuf = (unsigned short*)ws; ws += mixbytes;
  float* Sa = (float*)ws; ws += nstate * 4;
  float* Sb = (float*)ws; ws += nstate * 4;
  float* Sp = (float*)ws; ws += nstate * 4;
  float* Ia = (float*)ws; ws += nstate * 4;
  float* Ib = (float*)ws; ws += nstate * 4;
  float* Ip = (float*)ws; ws += nstate * 4;

  dim3 blk(256);
  dim3 blk8(512);
  const int wkv_grid = (int)(nstate / 256);               // 1024

  cast_w4_kernel<<<1024, blk, 0, stream>>>(Wk, Wv, Wr, Wo, Wkb, Wvb, Wrb, Wob);
  mix2_cast_kernel<<<2048, blk, 0, stream>>>(x, tmk, tmv, xkb, xvb);
  gemm8_one<0><<<256, blk8, 0, stream>>>(xkb, Wkb, kbuf);   // k (fp32)
  gemm8_one<1><<<256, blk8, 0, stream>>>(xvb, Wvb, vbuf);   // v (bf16)
  mix_cast_kernel<<<2048, blk, 0, stream>>>(x, tmr, xkb);   // xr into dead xkb
  gemm8_one<1><<<256, blk8, 0, stream>>>(xkb, Wrb, rbuf);   // r -> R2 (xvb dead)

  wkv_phase1<<<wkv_grid, blk, 0, stream>>>(kbuf, vbuf, tdec, Sa, Sb, Sp);
  wkv_phase2<<<(BB * CC + 255) / 256, blk, 0, stream>>>(tdec, Sa, Sb, Sp, Ia, Ib, Ip);
  wkv_phase3<<<wkv_grid, blk, 0, stream>>>(kbuf, vbuf, rbuf, tdec, tfir,
                                           Ia, Ib, Ip, rbuf);  // in-place gate

  gemm8_one<0><<<256, blk8, 0, stream>>>(rbuf, Wob, d_out);
}

// Round 8
// 258.696 us; speedup vs baseline: 4.8626x; 1.0588x over previous
//
#include <hip/hip_runtime.h>

#define BB 8
#define TT 2048
#define CC 1024
#define WKV_L 32
#define WKV_NCH (TT / WKV_L)   // 64 chunks
#define WKV_LOG_NCH 6

typedef __bf16 bf16x8_t __attribute__((ext_vector_type(8)));
typedef float f32x4_t __attribute__((ext_vector_type(4)));

__device__ __forceinline__ unsigned short f2bf(float f) {
  unsigned u = __float_as_uint(f);
  u += 0x7fffu + ((u >> 16) & 1u);   // round-to-nearest-even
  return (unsigned short)(u >> 16);
}
__device__ __forceinline__ float bf2f(unsigned short s) {
  return __uint_as_float(((unsigned)s) << 16);
}

#define GLOAD16(gp, lp)                                                        \
  __builtin_amdgcn_global_load_lds(                                            \
      (const __attribute__((address_space(1))) void*)(gp),                     \
      (__attribute__((address_space(3))) void*)(lp), 16, 0, 0)

// ---- fused time-shift mix: xk, xv, xr in ONE pass over x ----------------
__global__ __launch_bounds__(256) void mix3_cast_kernel(
    const float* __restrict__ x, const float* __restrict__ tmk,
    const float* __restrict__ tmv, const float* __restrict__ tmr,
    unsigned short* __restrict__ xk, unsigned short* __restrict__ xv,
    unsigned short* __restrict__ xr) {
  const size_t total4 = (size_t)BB * TT * CC / 4;
  for (size_t i = (size_t)blockIdx.x * blockDim.x + threadIdx.x; i < total4;
       i += (size_t)gridDim.x * blockDim.x) {
    size_t e = i * 4;
    int c = (int)(e & (CC - 1));
    int t = (int)((e / CC) & (TT - 1));
    float4 xv4 = ((const float4*)x)[i];
    float4 xp = make_float4(0.f, 0.f, 0.f, 0.f);
    if (t > 0) xp = ((const float4*)x)[i - CC / 4];
    float4 mk = *(const float4*)(tmk + c);
    float4 mv = *(const float4*)(tmv + c);
    float4 mr = *(const float4*)(tmr + c);
    ushort4 ok, ov, orr;
    ok.x = f2bf(xv4.x * mk.x + xp.x * (1.f - mk.x));
    ok.y = f2bf(xv4.y * mk.y + xp.y * (1.f - mk.y));
    ok.z = f2bf(xv4.z * mk.z + xp.z * (1.f - mk.z));
    ok.w = f2bf(xv4.w * mk.w + xp.w * (1.f - mk.w));
    ov.x = f2bf(xv4.x * mv.x + xp.x * (1.f - mv.x));
    ov.y = f2bf(xv4.y * mv.y + xp.y * (1.f - mv.y));
    ov.z = f2bf(xv4.z * mv.z + xp.z * (1.f - mv.z));
    ov.w = f2bf(xv4.w * mv.w + xp.w * (1.f - mv.w));
    orr.x = f2bf(xv4.x * mr.x + xp.x * (1.f - mr.x));
    orr.y = f2bf(xv4.y * mr.y + xp.y * (1.f - mr.y));
    orr.z = f2bf(xv4.z * mr.z + xp.z * (1.f - mr.z));
    orr.w = f2bf(xv4.w * mr.w + xp.w * (1.f - mr.w));
    *(ushort4*)(xk + e) = ok;
    *(ushort4*)(xv + e) = ov;
    *(ushort4*)(xr + e) = orr;
  }
}

// all 4 weight casts in one launch
__global__ __launch_bounds__(256) void cast_w4_kernel(
    const float* __restrict__ w0, const float* __restrict__ w1,
    const float* __restrict__ w2, const float* __restrict__ w3,
    unsigned short* __restrict__ o0, unsigned short* __restrict__ o1,
    unsigned short* __restrict__ o2, unsigned short* __restrict__ o3) {
  const int n4 = CC * CC / 4;   // per weight
  for (int i = blockIdx.x * blockDim.x + threadIdx.x; i < 4 * n4;
       i += gridDim.x * blockDim.x) {
    int sel = i / n4;
    int j = i - sel * n4;
    const float* w = sel == 0 ? w0 : sel == 1 ? w1 : sel == 2 ? w2 : w3;
    unsigned short* o = sel == 0 ? o0 : sel == 1 ? o1 : sel == 2 ? o2 : o3;
    float4 v = ((const float4*)w)[j];
    ushort4 u;
    u.x = f2bf(v.x); u.y = f2bf(v.y); u.z = f2bf(v.z); u.w = f2bf(v.w);
    ((ushort4*)o)[j] = u;
  }
}

// ---- 256x256 8-phase GEMM (T2+T3+T4+T5), unchanged from R7 --------------
#define NT8 (CC / 64)   // 16 K-tiles

template <typename EPI>
__device__ __forceinline__ void gemm8_body(unsigned short* lds8,
                                           const unsigned short* __restrict__ A,
                                           const unsigned short* __restrict__ Bm,
                                           int tm, int tn, EPI epi) {
  const int tid = threadIdx.x;
  const int lane = tid & 63;
  const int wid = tid >> 6;
  const int wr = wid >> 2;   // 0..1
  const int wc = wid & 3;    // 0..3
  const int fr = lane & 15;
  const int fk = lane >> 4;  // 0..3

  const int srow = tid >> 3;                          // 0..63
  const int gcol = (((tid & 7) ^ (srow & 7)) << 3);   // pre-swizzled global col
  const unsigned short* Ag = A + (size_t)(tm * 256 + srow) * CC + gcol;
  const unsigned short* Bg = Bm + (size_t)(tn * 256 + srow) * CC + gcol;
  const int ldst = tid << 3;                          // linear LDS dest (elems)

  const int rowA = wr * 16 + fr;
  const int rowB = wc * 16 + fr;
  const int sx0 = ((fk ^ (fr & 7)) << 3);             // read-side un-swizzle, kk=0
  const int sx1 = (((4 + fk) ^ (fr & 7)) << 3);       // kk=1

  bf16x8_t aF[4][2];      // current mh half: [i][kk]
  bf16x8_t bF[2][2][2];   // both nh halves:  [nh][j][kk]
  f32x4_t acc[8][4] = {};

#define STG_A(T, H)                                                            \
  {                                                                            \
    const unsigned short* g_ = Ag + (size_t)((H) * 128) * CC + (T) * 64;       \
    unsigned short* l_ = &lds8[(((T) & 1) << 14) + (H) * 8192 + ldst];         \
    GLOAD16(g_, l_);                                                           \
    GLOAD16(g_ + (size_t)64 * CC, l_ + 4096);                                  \
  }
#define STG_B(T, H)                                                            \
  {                                                                            \
    const unsigned short* g_ = Bg + (size_t)((H) * 128) * CC + (T) * 64;       \
    unsigned short* l_ = &lds8[32768 + (((T) & 1) << 14) + (H) * 8192 + ldst]; \
    GLOAD16(g_, l_);                                                           \
    GLOAD16(g_ + (size_t)64 * CC, l_ + 4096);                                  \
  }
#define LOADA(MH)                                                              \
  _Pragma("unroll") for (int i_ = 0; i_ < 4; ++i_) {                           \
    aF[i_][0] = *(const bf16x8_t*)&lds8[ab + ((MH) * 4 + i_) * 2048 + sx0];    \
    aF[i_][1] = *(const bf16x8_t*)&lds8[ab + ((MH) * 4 + i_) * 2048 + sx1];    \
  }
#define LOADB(NH)                                                              \
  _Pragma("unroll") for (int j_ = 0; j_ < 2; ++j_) {                           \
    bF[NH][j_][0] = *(const bf16x8_t*)&lds8[bb + ((NH) * 2 + j_) * 4096 + sx0];\
    bF[NH][j_][1] = *(const bf16x8_t*)&lds8[bb + ((NH) * 2 + j_) * 4096 + sx1];\
  }
#define MFMAQ(MH, NH)                                                          \
  _Pragma("unroll") for (int i_ = 0; i_ < 4; ++i_)                             \
  _Pragma("unroll") for (int j_ = 0; j_ < 2; ++j_) {                           \
    acc[(MH) * 4 + i_][(NH) * 2 + j_] = __builtin_amdgcn_mfma_f32_16x16x32_bf16( \
        aF[i_][0], bF[NH][j_][0], acc[(MH) * 4 + i_][(NH) * 2 + j_], 0, 0, 0); \
    acc[(MH) * 4 + i_][(NH) * 2 + j_] = __builtin_amdgcn_mfma_f32_16x16x32_bf16( \
        aF[i_][1], bF[NH][j_][1], acc[(MH) * 4 + i_][(NH) * 2 + j_], 0, 0, 0); \
  }

  STG_A(0, 0) STG_B(0, 0) STG_A(0, 1) STG_B(0, 1)
  STG_A(1, 0) STG_B(1, 0) STG_A(1, 1)
  asm volatile("s_waitcnt vmcnt(10)" ::: "memory");
  __builtin_amdgcn_s_barrier();

#pragma unroll
  for (int t = 0; t < NT8; ++t) {
    const int ab = ((t & 1) << 14) + rowA * 64;
    const int bb = 32768 + ((t & 1) << 14) + rowB * 64;
    LOADA(0) LOADB(0)
    if (t + 1 < NT8) { STG_B(t + 1, 1) }
    asm volatile("s_waitcnt vmcnt(8)" ::: "memory");
    __builtin_amdgcn_s_barrier();
    __builtin_amdgcn_s_setprio(1);
    MFMAQ(0, 0)
    __builtin_amdgcn_s_setprio(0);
    __builtin_amdgcn_s_barrier();
    LOADB(1)
    if (t + 2 < NT8) { STG_A(t + 2, 0) }
    __builtin_amdgcn_s_barrier();
    __builtin_amdgcn_s_setprio(1);
    MFMAQ(0, 1)
    __builtin_amdgcn_s_setprio(0);
    __builtin_amdgcn_s_barrier();
    LOADA(1)
    if (t + 2 < NT8) { STG_B(t + 2, 0) }
    __builtin_amdgcn_s_barrier();
    __builtin_amdgcn_s_setprio(1);
    MFMAQ(1, 0)
    __builtin_amdgcn_s_setprio(0);
    __builtin_amdgcn_s_barrier();
    if (t + 2 < NT8) { STG_A(t + 2, 1) }
    asm volatile("s_waitcnt vmcnt(10)" ::: "memory");
    __builtin_amdgcn_s_barrier();
    __builtin_amdgcn_s_setprio(1);
    MFMAQ(1, 1)
    __builtin_amdgcn_s_setprio(0);
    __builtin_amdgcn_s_barrier();
  }

#pragma unroll
  for (int im = 0; im < 8; ++im)
#pragma unroll
    for (int jn = 0; jn < 4; ++jn)
#pragma unroll
      for (int rg = 0; rg < 4; ++rg)
        epi((size_t)(tm * 256 + wr * 16 + im * 32 + (fk << 2) + rg) * CC +
                (size_t)(tn * 256 + wc * 16 + jn * 64 + fr),
            acc[im][jn][rg]);
#undef STG_A
#undef STG_B
#undef LOADA
#undef LOADB
#undef MFMAQ
}

// single GEMM (256 blocks, XCD-swizzled), fp32 or bf16 out
template <int OUT_BF16>
__global__ __launch_bounds__(512, 2) void gemm8_one(const unsigned short* __restrict__ A,
                         const unsigned short* __restrict__ Bm,
                         void* __restrict__ Cm) {
  __shared__ unsigned short lds8[65536];   // 128 KB
  int orig = blockIdx.x;
  int wg = (orig & 7) * 32 + (orig >> 3);
  int tm = wg >> 2;
  int tn = wg & 3;
  if (OUT_BF16)
    gemm8_body(lds8, A, Bm, tm, tn,
               [&](size_t off, float val) { ((unsigned short*)Cm)[off] = f2bf(val); });
  else
    gemm8_body(lds8, A, Bm, tm, tn,
               [&](size_t off, float val) { ((float*)Cm)[off] = val; });
}

// ---- Chunk-parallel WKV scan, anchor-decay formulation ------------------
// State (aa, bb, pp) represents A = aa*e^pp, B = bb*e^pp. Decay is pp += w
// (no exp). Renorm (rescale aa,bb, pp=kt) only when d = kt-pp > 8 -> E =
// exp(d) <= e^8 bounded; bb is monotone nondecreasing from 1 (no underflow);
// aa <= L*e^8*|v| (no overflow). Algebraically identical to the reference's
// max-stabilized recurrence; only rounding differs.
__global__ __launch_bounds__(256) void wkv_phase1(const float* __restrict__ k,
                           const unsigned short* __restrict__ v,
                           const float* __restrict__ wdec,
                           float* __restrict__ Sa, float* __restrict__ Sb,
                           float* __restrict__ Sp) {
  int idx = blockIdx.x * blockDim.x + threadIdx.x;  // (b*NCH + j)*CC + c
  int c = idx & (CC - 1);
  int bj = idx >> 10;
  int j = bj & (WKV_NCH - 1);
  int b = bj >> WKV_LOG_NCH;
  float w = -__expf(wdec[c]);
  size_t base = ((size_t)b * TT + (size_t)j * WKV_L) * CC + c;
  float aa = 0.f, bb = 0.f, pp = -1e38f;
  for (int t = 0; t < WKV_L; ++t) {
    size_t off = base + (size_t)t * CC;
    float kt = k[off];
    float vt = bf2f(v[off]);
    pp += w;
    float d = kt - pp;
    if (d > 8.f) {
      float s = __expf(-d);
      aa *= s; bb *= s; pp = kt; d = 0.f;
    }
    float E = __expf(d);
    aa = fmaf(E, vt, aa);
    bb += E;
  }
  Sa[idx] = aa; Sb[idx] = bb; Sp[idx] = pp;
}

// serial scan over chunk summaries (max-stabilized; any (a,b,p) factorization
// of the chunk summaries is valid input).
__global__ __launch_bounds__(256) void wkv_phase2(const float* __restrict__ wdec,
                           const float* __restrict__ Sa, const float* __restrict__ Sb,
                           const float* __restrict__ Sp,
                           float* __restrict__ Ia, float* __restrict__ Ib,
                           float* __restrict__ Ip) {
  int idx = blockIdx.x * blockDim.x + threadIdx.x;  // b*CC + c
  if (idx >= BB * CC) return;
  int c = idx & (CC - 1);
  int b = idx >> 10;
  float wL = -__expf(wdec[c]) * (float)WKV_L;
  float aa = 0.f, bb = 0.f, pp = -1e38f;
  for (int j = 0; j < WKV_NCH; ++j) {
    size_t s = (size_t)(b * WKV_NCH + j) * CC + c;
    Ia[s] = aa; Ib[s] = bb; Ip[s] = pp;
    float pd = pp + wL;
    float ps = Sp[s];
    float q = fmaxf(pd, ps);
    float e1 = __expf(pd - q);
    float e2 = __expf(ps - q);
    aa = fmaf(e1, aa, e2 * Sa[s]);
    bb = fmaf(e1, bb, e2 * Sb[s]);
    pp = q;
  }
}

// phase3: anchor-decay replay + fused sigmoid(r)*y, in-place (out==r OK).
__global__ __launch_bounds__(256) void wkv_phase3(const float* __restrict__ k,
                           const unsigned short* __restrict__ v,
                           const unsigned short* r,
                           const float* __restrict__ wdec,
                           const float* __restrict__ u,
                           const float* __restrict__ Ia, const float* __restrict__ Ib,
                           const float* __restrict__ Ip,
                           unsigned short* out) {
  int idx = blockIdx.x * blockDim.x + threadIdx.x;  // (b*NCH + j)*CC + c
  int c = idx & (CC - 1);
  int bj = idx >> 10;
  int j = bj & (WKV_NCH - 1);
  int b = bj >> WKV_LOG_NCH;
  float w = -__expf(wdec[c]);
  float uu = u[c];
  float aa = Ia[idx], bb = Ib[idx], pp = Ip[idx];
  size_t base = ((size_t)b * TT + (size_t)j * WKV_L) * CC + c;
  for (int t = 0; t < WKV_L; ++t) {
    size_t off = base + (size_t)t * CC;
    float kt = k[off];
    float vt = bf2f(v[off]);
    // y uses pre-decay state: y = (A + e^{u+kt} v)/(B + e^{u+kt})
    float dy = fminf(uu + kt - pp, 60.f);   // clamp: beyond 60, y == vt to 1e-20
    float Eu = __expf(dy);
    float y = fmaf(Eu, vt, aa) / (bb + Eu);
    float rt = bf2f(r[off]);
    float sr = 1.f / (1.f + __expf(-rt));
    out[off] = f2bf(sr * y);
    // decay + (rare) renorm + accumulate
    pp += w;
    float d = kt - pp;
    if (d > 8.f) {
      float s = __expf(-d);
      aa *= s; bb *= s; pp = kt; d = 0.f;
    }
    float E = __expf(d);
    aa = fmaf(E, vt, aa);
    bb += E;
  }
}

extern "C" void kernel_launch(void* const* d_in, const int* in_sizes, int n_in,
                              void* d_out, int out_size, void* d_ws, size_t ws_size,
                              hipStream_t stream) {
  const float* x    = (const float*)d_in[0];
  const float* tdec = (const float*)d_in[1];
  const float* tfir = (const float*)d_in[2];
  const float* tmk  = (const float*)d_in[3];
  const float* tmv  = (const float*)d_in[4];
  const float* tmr  = (const float*)d_in[5];
  const float* Wk   = (const float*)d_in[6];
  const float* Wv   = (const float*)d_in[7];
  const float* Wr   = (const float*)d_in[8];
  const float* Wo   = (const float*)d_in[9];

  const size_t M = (size_t)BB * TT;     // 16384
  const size_t mixbytes = M * CC * 2;   // 33.5 MB
  const size_t wbytes = (size_t)CC * CC * 2;
  const size_t nstate = (size_t)BB * WKV_NCH * CC;   // 512K

  // Overlay plan (~218 MB; ws >= 279 MB confirmed by R4's big-path run):
  //   xkb: mix3-out -> k-gemm; dead -> rbuf (r-gemm out, p3 in-place, final gemm A)
  //   xvb: mix3-out -> v-gemm; dead after
  //   xrb: mix3-out -> r-gemm; dead after
  char* ws = (char*)d_ws;
  unsigned short* xkb = (unsigned short*)ws;  ws += mixbytes;
  unsigned short* xvb = (unsigned short*)ws;  ws += mixbytes;
  unsigned short* xrb = (unsigned short*)ws;  ws += mixbytes;
  unsigned short* rbuf = xkb;                 // alias (xkb dead after k-gemm)
  unsigned short* Wkb = (unsigned short*)ws; ws += wbytes;
  unsigned short* Wvb = (unsigned short*)ws; ws += wbytes;
  unsigned short* Wrb = (unsigned short*)ws; ws += wbytes;
  unsigned short* Wob = (unsigned short*)ws; ws += wbytes;
  float* kbuf = (float*)ws;                   ws += M * CC * 4;
  unsigned short* vbuf = (unsigned short*)ws; ws += mixbytes;
  float* Sa = (float*)ws; ws += nstate * 4;
  float* Sb = (float*)ws; ws += nstate * 4;
  float* Sp = (float*)ws; ws += nstate * 4;
  float* Ia = (float*)ws; ws += nstate * 4;
  float* Ib = (float*)ws; ws += nstate * 4;
  float* Ip = (float*)ws; ws += nstate * 4;

  dim3 blk(256);
  dim3 blk8(512);
  const int wkv_grid = (int)(nstate / 256);   // 2048

  cast_w4_kernel<<<1024, blk, 0, stream>>>(Wk, Wv, Wr, Wo, Wkb, Wvb, Wrb, Wob);
  mix3_cast_kernel<<<2048, blk, 0, stream>>>(x, tmk, tmv, tmr, xkb, xvb, xrb);
  gemm8_one<0><<<256, blk8, 0, stream>>>(xkb, Wkb, kbuf);   // k (fp32)
  gemm8_one<1><<<256, blk8, 0, stream>>>(xvb, Wvb, vbuf);   // v (bf16)
  gemm8_one<1><<<256, blk8, 0, stream>>>(xrb, Wrb, rbuf);   // r (bf16, into dead xkb)

  wkv_phase1<<<wkv_grid, blk, 0, stream>>>(kbuf, vbuf, tdec, Sa, Sb, Sp);
  wkv_phase2<<<(BB * CC + 255) / 256, blk, 0, stream>>>(tdec, Sa, Sb, Sp, Ia, Ib, Ip);
  wkv_phase3<<<wkv_grid, blk, 0, stream>>>(kbuf, vbuf, rbuf, tdec, tfir,
                                           Ia, Ib, Ip, rbuf);  // in-place gate

  gemm8_one<0><<<256, blk8, 0, stream>>>(rbuf, Wob, d_out);
}

// Round 9
// 249.967 us; speedup vs baseline: 5.0324x; 1.0349x over previous
//
#include <hip/hip_runtime.h>

#define BB 8
#define TT 2048
#define CC 1024
#define WKV_L 32
#define WKV_NCH (TT / WKV_L)   // 64 chunks
#define WKV_LOG_NCH 6

typedef __bf16 bf16x8_t __attribute__((ext_vector_type(8)));
typedef float f32x4_t __attribute__((ext_vector_type(4)));
typedef unsigned short ushort8_t __attribute__((ext_vector_type(8)));

__device__ __forceinline__ unsigned short f2bf(float f) {
  unsigned u = __float_as_uint(f);
  u += 0x7fffu + ((u >> 16) & 1u);   // round-to-nearest-even
  return (unsigned short)(u >> 16);
}
__device__ __forceinline__ float bf2f(unsigned short s) {
  return __uint_as_float(((unsigned)s) << 16);
}

#define GLOAD16(gp, lp)                                                        \
  __builtin_amdgcn_global_load_lds(                                            \
      (const __attribute__((address_space(1))) void*)(gp),                     \
      (__attribute__((address_space(3))) void*)(lp), 16, 0, 0)

// ---- fused time-shift mix: xk, xv, xr in ONE pass, 32B/lane -------------
__global__ __launch_bounds__(256) void mix3_cast_kernel(
    const float* __restrict__ x, const float* __restrict__ tmk,
    const float* __restrict__ tmv, const float* __restrict__ tmr,
    unsigned short* __restrict__ xk, unsigned short* __restrict__ xv,
    unsigned short* __restrict__ xr) {
  const size_t total8 = (size_t)BB * TT * CC / 8;
  for (size_t i = (size_t)blockIdx.x * blockDim.x + threadIdx.x; i < total8;
       i += (size_t)gridDim.x * blockDim.x) {
    size_t e = i * 8;
    int c = (int)(e & (CC - 1));
    int t = (int)((e / CC) & (TT - 1));
    float4 xa = ((const float4*)x)[2 * i];
    float4 xb = ((const float4*)x)[2 * i + 1];
    float4 pa = make_float4(0.f, 0.f, 0.f, 0.f), pb = pa;
    if (t > 0) {
      pa = ((const float4*)x)[2 * i - 256];
      pb = ((const float4*)x)[2 * i - 255];
    }
    float4 mka = *(const float4*)(tmk + c), mkb = *(const float4*)(tmk + c + 4);
    float4 mva = *(const float4*)(tmv + c), mvb = *(const float4*)(tmv + c + 4);
    float4 mra = *(const float4*)(tmr + c), mrb = *(const float4*)(tmr + c + 4);
    ushort8_t ok, ov, orr;
#define MIX1(dst, idx, xv_, pv_, m_)                                           \
    dst[idx] = f2bf(xv_ * m_ + pv_ * (1.f - m_));
    MIX1(ok, 0, xa.x, pa.x, mka.x) MIX1(ok, 1, xa.y, pa.y, mka.y)
    MIX1(ok, 2, xa.z, pa.z, mka.z) MIX1(ok, 3, xa.w, pa.w, mka.w)
    MIX1(ok, 4, xb.x, pb.x, mkb.x) MIX1(ok, 5, xb.y, pb.y, mkb.y)
    MIX1(ok, 6, xb.z, pb.z, mkb.z) MIX1(ok, 7, xb.w, pb.w, mkb.w)
    MIX1(ov, 0, xa.x, pa.x, mva.x) MIX1(ov, 1, xa.y, pa.y, mva.y)
    MIX1(ov, 2, xa.z, pa.z, mva.z) MIX1(ov, 3, xa.w, pa.w, mva.w)
    MIX1(ov, 4, xb.x, pb.x, mvb.x) MIX1(ov, 5, xb.y, pb.y, mvb.y)
    MIX1(ov, 6, xb.z, pb.z, mvb.z) MIX1(ov, 7, xb.w, pb.w, mvb.w)
    MIX1(orr, 0, xa.x, pa.x, mra.x) MIX1(orr, 1, xa.y, pa.y, mra.y)
    MIX1(orr, 2, xa.z, pa.z, mra.z) MIX1(orr, 3, xa.w, pa.w, mra.w)
    MIX1(orr, 4, xb.x, pb.x, mrb.x) MIX1(orr, 5, xb.y, pb.y, mrb.y)
    MIX1(orr, 6, xb.z, pb.z, mrb.z) MIX1(orr, 7, xb.w, pb.w, mrb.w)
#undef MIX1
    *(ushort8_t*)(xk + e) = ok;
    *(ushort8_t*)(xv + e) = ov;
    *(ushort8_t*)(xr + e) = orr;
  }
}

// all 4 weight casts in one launch
__global__ __launch_bounds__(256) void cast_w4_kernel(
    const float* __restrict__ w0, const float* __restrict__ w1,
    const float* __restrict__ w2, const float* __restrict__ w3,
    unsigned short* __restrict__ o0, unsigned short* __restrict__ o1,
    unsigned short* __restrict__ o2, unsigned short* __restrict__ o3) {
  const int n4 = CC * CC / 4;   // per weight
  for (int i = blockIdx.x * blockDim.x + threadIdx.x; i < 4 * n4;
       i += gridDim.x * blockDim.x) {
    int sel = i / n4;
    int j = i - sel * n4;
    const float* w = sel == 0 ? w0 : sel == 1 ? w1 : sel == 2 ? w2 : w3;
    unsigned short* o = sel == 0 ? o0 : sel == 1 ? o1 : sel == 2 ? o2 : o3;
    float4 v = ((const float4*)w)[j];
    ushort4 u;
    u.x = f2bf(v.x); u.y = f2bf(v.y); u.z = f2bf(v.z); u.w = f2bf(v.w);
    ((ushort4*)o)[j] = u;
  }
}

// ---- 256x256 8-phase GEMM (T2+T3+T4+T5) ---------------------------------
#define NT8 (CC / 64)   // 16 K-tiles

template <typename EPI>
__device__ __forceinline__ void gemm8_body(unsigned short* lds8,
                                           const unsigned short* __restrict__ A,
                                           const unsigned short* __restrict__ Bm,
                                           int tm, int tn, EPI epi) {
  const int tid = threadIdx.x;
  const int lane = tid & 63;
  const int wid = tid >> 6;
  const int wr = wid >> 2;   // 0..1
  const int wc = wid & 3;    // 0..3
  const int fr = lane & 15;
  const int fk = lane >> 4;  // 0..3

  const int srow = tid >> 3;                          // 0..63
  const int gcol = (((tid & 7) ^ (srow & 7)) << 3);   // pre-swizzled global col
  const unsigned short* Ag = A + (size_t)(tm * 256 + srow) * CC + gcol;
  const unsigned short* Bg = Bm + (size_t)(tn * 256 + srow) * CC + gcol;
  const int ldst = tid << 3;                          // linear LDS dest (elems)

  const int rowA = wr * 16 + fr;
  const int rowB = wc * 16 + fr;
  const int sx0 = ((fk ^ (fr & 7)) << 3);             // read-side un-swizzle, kk=0
  const int sx1 = (((4 + fk) ^ (fr & 7)) << 3);       // kk=1

  bf16x8_t aF[4][2];      // current mh half: [i][kk]
  bf16x8_t bF[2][2][2];   // both nh halves:  [nh][j][kk]
  f32x4_t acc[8][4] = {};

#define STG_A(T, H)                                                            \
  {                                                                            \
    const unsigned short* g_ = Ag + (size_t)((H) * 128) * CC + (T) * 64;       \
    unsigned short* l_ = &lds8[(((T) & 1) << 14) + (H) * 8192 + ldst];         \
    GLOAD16(g_, l_);                                                           \
    GLOAD16(g_ + (size_t)64 * CC, l_ + 4096);                                  \
  }
#define STG_B(T, H)                                                            \
  {                                                                            \
    const unsigned short* g_ = Bg + (size_t)((H) * 128) * CC + (T) * 64;       \
    unsigned short* l_ = &lds8[32768 + (((T) & 1) << 14) + (H) * 8192 + ldst]; \
    GLOAD16(g_, l_);                                                           \
    GLOAD16(g_ + (size_t)64 * CC, l_ + 4096);                                  \
  }
#define LOADA(MH)                                                              \
  _Pragma("unroll") for (int i_ = 0; i_ < 4; ++i_) {                           \
    aF[i_][0] = *(const bf16x8_t*)&lds8[ab + ((MH) * 4 + i_) * 2048 + sx0];    \
    aF[i_][1] = *(const bf16x8_t*)&lds8[ab + ((MH) * 4 + i_) * 2048 + sx1];    \
  }
#define LOADB(NH)                                                              \
  _Pragma("unroll") for (int j_ = 0; j_ < 2; ++j_) {                           \
    bF[NH][j_][0] = *(const bf16x8_t*)&lds8[bb + ((NH) * 2 + j_) * 4096 + sx0];\
    bF[NH][j_][1] = *(const bf16x8_t*)&lds8[bb + ((NH) * 2 + j_) * 4096 + sx1];\
  }
#define MFMAQ(MH, NH)                                                          \
  _Pragma("unroll") for (int i_ = 0; i_ < 4; ++i_)                             \
  _Pragma("unroll") for (int j_ = 0; j_ < 2; ++j_) {                           \
    acc[(MH) * 4 + i_][(NH) * 2 + j_] = __builtin_amdgcn_mfma_f32_16x16x32_bf16( \
        aF[i_][0], bF[NH][j_][0], acc[(MH) * 4 + i_][(NH) * 2 + j_], 0, 0, 0); \
    acc[(MH) * 4 + i_][(NH) * 2 + j_] = __builtin_amdgcn_mfma_f32_16x16x32_bf16( \
        aF[i_][1], bF[NH][j_][1], acc[(MH) * 4 + i_][(NH) * 2 + j_], 0, 0, 0); \
  }

  STG_A(0, 0) STG_B(0, 0) STG_A(0, 1) STG_B(0, 1)
  STG_A(1, 0) STG_B(1, 0) STG_A(1, 1)
  asm volatile("s_waitcnt vmcnt(10)" ::: "memory");
  __builtin_amdgcn_s_barrier();

#pragma unroll
  for (int t = 0; t < NT8; ++t) {
    const int ab = ((t & 1) << 14) + rowA * 64;
    const int bb = 32768 + ((t & 1) << 14) + rowB * 64;
    LOADA(0) LOADB(0)
    if (t + 1 < NT8) { STG_B(t + 1, 1) }
    asm volatile("s_waitcnt vmcnt(8)" ::: "memory");
    __builtin_amdgcn_s_barrier();
    __builtin_amdgcn_s_setprio(1);
    MFMAQ(0, 0)
    __builtin_amdgcn_s_setprio(0);
    __builtin_amdgcn_s_barrier();
    LOADB(1)
    if (t + 2 < NT8) { STG_A(t + 2, 0) }
    __builtin_amdgcn_s_barrier();
    __builtin_amdgcn_s_setprio(1);
    MFMAQ(0, 1)
    __builtin_amdgcn_s_setprio(0);
    __builtin_amdgcn_s_barrier();
    LOADA(1)
    if (t + 2 < NT8) { STG_B(t + 2, 0) }
    __builtin_amdgcn_s_barrier();
    __builtin_amdgcn_s_setprio(1);
    MFMAQ(1, 0)
    __builtin_amdgcn_s_setprio(0);
    __builtin_amdgcn_s_barrier();
    if (t + 2 < NT8) { STG_A(t + 2, 1) }
    asm volatile("s_waitcnt vmcnt(10)" ::: "memory");
    __builtin_amdgcn_s_barrier();
    __builtin_amdgcn_s_setprio(1);
    MFMAQ(1, 1)
    __builtin_amdgcn_s_setprio(0);
    __builtin_amdgcn_s_barrier();
  }

#pragma unroll
  for (int im = 0; im < 8; ++im)
#pragma unroll
    for (int jn = 0; jn < 4; ++jn)
#pragma unroll
      for (int rg = 0; rg < 4; ++rg)
        epi((size_t)(tm * 256 + wr * 16 + im * 32 + (fk << 2) + rg) * CC +
                (size_t)(tn * 256 + wc * 16 + jn * 64 + fr),
            acc[im][jn][rg]);
#undef STG_A
#undef STG_B
#undef LOADA
#undef LOADB
#undef MFMAQ
}

// merged k/v/r projection: 768 blocks (3/CU -> write-drain overlaps compute),
// XCD-swizzled (768%8==0, bijective). All outputs bf16 (k included; input-
// perturbation class error, ~1% weight shift in wkv).
__global__ __launch_bounds__(512, 2) void gemm8_kvr(
    const unsigned short* __restrict__ xk, const unsigned short* __restrict__ xv,
    const unsigned short* __restrict__ xr, const unsigned short* __restrict__ Wk,
    const unsigned short* __restrict__ Wv, const unsigned short* __restrict__ Wr,
    unsigned short* __restrict__ kout, unsigned short* __restrict__ vout,
    unsigned short* __restrict__ rout) {
  __shared__ unsigned short lds8[65536];   // 128 KB
  int orig = blockIdx.x;
  int wg = (orig & 7) * 96 + (orig >> 3);
  int which = wg >> 8;        // 256 tiles per matrix
  int rr = wg & 255;
  int tm = rr >> 2;           // tn-fast within XCD chunk
  int tn = rr & 3;
  const unsigned short* A = which == 0 ? xk : which == 1 ? xv : xr;
  const unsigned short* Bm = which == 0 ? Wk : which == 1 ? Wv : Wr;
  unsigned short* o = which == 0 ? kout : which == 1 ? vout : rout;
  gemm8_body(lds8, A, Bm, tm, tn,
             [&](size_t off, float val) { o[off] = f2bf(val); });
}

// single GEMM (256 blocks, XCD-swizzled), fp32 out (final projection)
__global__ __launch_bounds__(512, 2) void gemm8_one(const unsigned short* __restrict__ A,
                         const unsigned short* __restrict__ Bm,
                         float* __restrict__ Cm) {
  __shared__ unsigned short lds8[65536];   // 128 KB
  int orig = blockIdx.x;
  int wg = (orig & 7) * 32 + (orig >> 3);
  int tm = wg >> 2;
  int tn = wg & 3;
  gemm8_body(lds8, A, Bm, tm, tn,
             [&](size_t off, float val) { Cm[off] = val; });
}

// ---- Chunk-parallel WKV scan, anchor-decay, 2 channels/thread -----------
// Dual independent recurrence chains per thread hide serial exp latency.
__global__ __launch_bounds__(256) void wkv_phase1(const unsigned short* __restrict__ k,
                           const unsigned short* __restrict__ v,
                           const float* __restrict__ wdec,
                           float* __restrict__ Sa, float* __restrict__ Sb,
                           float* __restrict__ Sp) {
  int idx = blockIdx.x * blockDim.x + threadIdx.x;  // (b*NCH + j)*(CC/2) + c2
  int c = (idx & (CC / 2 - 1)) << 1;
  int bj = idx >> 9;
  int j = bj & (WKV_NCH - 1);
  int b = bj >> WKV_LOG_NCH;
  float w0 = -__expf(wdec[c]), w1 = -__expf(wdec[c + 1]);
  size_t base = ((size_t)b * TT + (size_t)j * WKV_L) * CC + c;
  float aa0 = 0.f, bb0 = 0.f, pp0 = -1e38f;
  float aa1 = 0.f, bb1 = 0.f, pp1 = -1e38f;
  for (int t = 0; t < WKV_L; ++t) {
    size_t off = base + (size_t)t * CC;
    ushort2 kk = *(const ushort2*)(k + off);
    ushort2 vv = *(const ushort2*)(v + off);
    float k0 = bf2f(kk.x), k1 = bf2f(kk.y);
    float v0 = bf2f(vv.x), v1 = bf2f(vv.y);
    pp0 += w0; pp1 += w1;
    float d0 = k0 - pp0, d1 = k1 - pp1;
    if (d0 > 8.f) { float s = __expf(-d0); aa0 *= s; bb0 *= s; pp0 = k0; d0 = 0.f; }
    if (d1 > 8.f) { float s = __expf(-d1); aa1 *= s; bb1 *= s; pp1 = k1; d1 = 0.f; }
    float E0 = __expf(d0), E1 = __expf(d1);
    aa0 = fmaf(E0, v0, aa0); bb0 += E0;
    aa1 = fmaf(E1, v1, aa1); bb1 += E1;
  }
  size_t s = (size_t)bj * CC + c;
  *(float2*)(Sa + s) = make_float2(aa0, aa1);
  *(float2*)(Sb + s) = make_float2(bb0, bb1);
  *(float2*)(Sp + s) = make_float2(pp0, pp1);
}

// serial scan over chunk summaries -> incoming state per chunk
__global__ __launch_bounds__(256) void wkv_phase2(const float* __restrict__ wdec,
                           const float* __restrict__ Sa, const float* __restrict__ Sb,
                           const float* __restrict__ Sp,
                           float* __restrict__ Ia, float* __restrict__ Ib,
                           float* __restrict__ Ip) {
  int idx = blockIdx.x * blockDim.x + threadIdx.x;  // b*CC + c
  if (idx >= BB * CC) return;
  int c = idx & (CC - 1);
  int b = idx >> 10;
  float wL = -__expf(wdec[c]) * (float)WKV_L;
  float aa = 0.f, bb = 0.f, pp = -1e38f;
  for (int j = 0; j < WKV_NCH; ++j) {
    size_t s = (size_t)(b * WKV_NCH + j) * CC + c;
    Ia[s] = aa; Ib[s] = bb; Ip[s] = pp;
    float pd = pp + wL;
    float ps = Sp[s];
    float q = fmaxf(pd, ps);
    float e1 = __expf(pd - q);
    float e2 = __expf(ps - q);
    aa = fmaf(e1, aa, e2 * Sa[s]);
    bb = fmaf(e1, bb, e2 * Sb[s]);
    pp = q;
  }
}

// phase3: anchor-decay replay + fused sigmoid(r)*y, 2 ch/thread, in-place
__global__ __launch_bounds__(256) void wkv_phase3(const unsigned short* __restrict__ k,
                           const unsigned short* __restrict__ v,
                           const unsigned short* r,
                           const float* __restrict__ wdec,
                           const float* __restrict__ u,
                           const float* __restrict__ Ia, const float* __restrict__ Ib,
                           const float* __restrict__ Ip,
                           unsigned short* out) {
  int idx = blockIdx.x * blockDim.x + threadIdx.x;
  int c = (idx & (CC / 2 - 1)) << 1;
  int bj = idx >> 9;
  int j = bj & (WKV_NCH - 1);
  int b = bj >> WKV_LOG_NCH;
  float w0 = -__expf(wdec[c]), w1 = -__expf(wdec[c + 1]);
  float u0 = u[c], u1 = u[c + 1];
  size_t st = (size_t)bj * CC + c;
  float2 a2 = *(const float2*)(Ia + st);
  float2 b2 = *(const float2*)(Ib + st);
  float2 p2 = *(const float2*)(Ip + st);
  float aa0 = a2.x, bb0 = b2.x, pp0 = p2.x;
  float aa1 = a2.y, bb1 = b2.y, pp1 = p2.y;
  size_t base = ((size_t)b * TT + (size_t)j * WKV_L) * CC + c;
  for (int t = 0; t < WKV_L; ++t) {
    size_t off = base + (size_t)t * CC;
    ushort2 kk = *(const ushort2*)(k + off);
    ushort2 vv = *(const ushort2*)(v + off);
    ushort2 rr2 = *(const ushort2*)(r + off);
    float k0 = bf2f(kk.x), k1 = bf2f(kk.y);
    float v0 = bf2f(vv.x), v1 = bf2f(vv.y);
    // y from pre-decay state
    float dy0 = fminf(u0 + k0 - pp0, 60.f);
    float dy1 = fminf(u1 + k1 - pp1, 60.f);
    float Eu0 = __expf(dy0), Eu1 = __expf(dy1);
    float y0 = fmaf(Eu0, v0, aa0) / (bb0 + Eu0);
    float y1 = fmaf(Eu1, v1, aa1) / (bb1 + Eu1);
    float sr0 = 1.f / (1.f + __expf(-bf2f(rr2.x)));
    float sr1 = 1.f / (1.f + __expf(-bf2f(rr2.y)));
    ushort2 o;
    o.x = f2bf(sr0 * y0);
    o.y = f2bf(sr1 * y1);
    *(ushort2*)(out + off) = o;
    // decay + rare renorm + accumulate
    pp0 += w0; pp1 += w1;
    float d0 = k0 - pp0, d1 = k1 - pp1;
    if (d0 > 8.f) { float s = __expf(-d0); aa0 *= s; bb0 *= s; pp0 = k0; d0 = 0.f; }
    if (d1 > 8.f) { float s = __expf(-d1); aa1 *= s; bb1 *= s; pp1 = k1; d1 = 0.f; }
    float E0 = __expf(d0), E1 = __expf(d1);
    aa0 = fmaf(E0, v0, aa0); bb0 += E0;
    aa1 = fmaf(E1, v1, aa1); bb1 += E1;
  }
}

extern "C" void kernel_launch(void* const* d_in, const int* in_sizes, int n_in,
                              void* d_out, int out_size, void* d_ws, size_t ws_size,
                              hipStream_t stream) {
  const float* x    = (const float*)d_in[0];
  const float* tdec = (const float*)d_in[1];
  const float* tfir = (const float*)d_in[2];
  const float* tmk  = (const float*)d_in[3];
  const float* tmv  = (const float*)d_in[4];
  const float* tmr  = (const float*)d_in[5];
  const float* Wk   = (const float*)d_in[6];
  const float* Wv   = (const float*)d_in[7];
  const float* Wr   = (const float*)d_in[8];
  const float* Wo   = (const float*)d_in[9];

  const size_t M = (size_t)BB * TT;     // 16384
  const size_t mixbytes = M * CC * 2;   // 33.5 MB
  const size_t wbytes = (size_t)CC * CC * 2;
  const size_t nstate = (size_t)BB * WKV_NCH * CC;   // 512K

  // Layout (~209 MB peak; ws >= 218 proven by R8):
  //   xk/xv/xr: mix3 out -> kvr GEMM A's; dead after -> states overlay here
  //   k/v/r: kvr GEMM outs (all bf16); p3 gates in-place into rbuf
  char* ws = (char*)d_ws;
  unsigned short* xkb = (unsigned short*)ws;  ws += mixbytes;
  unsigned short* xvb = (unsigned short*)ws;  ws += mixbytes;
  unsigned short* xrb = (unsigned short*)ws;  ws += mixbytes;
  unsigned short* Wkb = (unsigned short*)ws; ws += wbytes;
  unsigned short* Wvb = (unsigned short*)ws; ws += wbytes;
  unsigned short* Wrb = (unsigned short*)ws; ws += wbytes;
  unsigned short* Wob = (unsigned short*)ws; ws += wbytes;
  unsigned short* kbuf = (unsigned short*)ws; ws += mixbytes;
  unsigned short* vbuf = (unsigned short*)ws; ws += mixbytes;
  unsigned short* rbuf = (unsigned short*)ws; ws += mixbytes;
  // states overlay the dead xk/xv regions (12.6 MB < 67 MB)
  char* so = (char*)xkb;
  float* Sa = (float*)so; so += nstate * 4;
  float* Sb = (float*)so; so += nstate * 4;
  float* Sp = (float*)so; so += nstate * 4;
  float* Ia = (float*)so; so += nstate * 4;
  float* Ib = (float*)so; so += nstate * 4;
  float* Ip = (float*)so; so += nstate * 4;

  dim3 blk(256);
  dim3 blk8(512);
  const int wkv_grid = (int)(nstate / 2 / 256);   // 1024

  cast_w4_kernel<<<1024, blk, 0, stream>>>(Wk, Wv, Wr, Wo, Wkb, Wvb, Wrb, Wob);
  mix3_cast_kernel<<<2048, blk, 0, stream>>>(x, tmk, tmv, tmr, xkb, xvb, xrb);
  gemm8_kvr<<<768, blk8, 0, stream>>>(xkb, xvb, xrb, Wkb, Wvb, Wrb,
                                      kbuf, vbuf, rbuf);

  wkv_phase1<<<wkv_grid, blk, 0, stream>>>(kbuf, vbuf, tdec, Sa, Sb, Sp);
  wkv_phase2<<<(BB * CC + 255) / 256, blk, 0, stream>>>(tdec, Sa, Sb, Sp, Ia, Ib, Ip);
  wkv_phase3<<<wkv_grid, blk, 0, stream>>>(kbuf, vbuf, rbuf, tdec, tfir,
                                           Ia, Ib, Ip, rbuf);  // in-place gate

  gemm8_one<<<256, blk8, 0, stream>>>(rbuf, Wob, (float*)d_out);
}